// Round 3
// baseline (900.945 us; speedup 1.0000x reference)
//
#include <hip/hip_runtime.h>
#include <math.h>

#define NB 2
#define NN 1024
#define HH 768
#define MAXW 30
#define KTOP 409
#define BANDCAP 4096
#define BAND_TAU 2e-2f
#define CHT 120  // tile-chunk stride for At buffer (two passes: 120 + 117)

typedef __attribute__((ext_vector_type(4))) float f32x4;
typedef __attribute__((ext_vector_type(8))) __bf16 bf16x8;
typedef __attribute__((ext_vector_type(8))) unsigned short us8;

// fp32 tile constants (pq + gather kernels, validated round 1/2)
constexpr int MT = 64, NT = 256, KT = 32;
constexpr int ASTR = MT + 4;
constexpr int BSTR = NT + 4;

__device__ __forceinline__ float gelu_f(float z) {
  return 0.5f * z * (1.0f + erff(z * 0.70710678118654752440f));
}
__device__ __forceinline__ unsigned f2key(float f) {
  unsigned u = __float_as_uint(f);
  return (u & 0x80000000u) ? ~u : (u | 0x80000000u);
}
__device__ __forceinline__ float key2f(unsigned k) {
  unsigned u = (k & 0x80000000u) ? (k & 0x7fffffffu) : ~k;
  return __uint_as_float(u);
}
__device__ __forceinline__ unsigned short f2bf_rn(float f) {
  unsigned u = __float_as_uint(f);
  unsigned r = u + 0x7fffu + ((u >> 16) & 1u);
  return (unsigned short)(r >> 16);
}
__device__ __forceinline__ void async_copy16(const void* g, void* l) {
  __builtin_amdgcn_global_load_lds(
      (const __attribute__((address_space(1))) unsigned int*)g,
      (__attribute__((address_space(3))) unsigned int*)l, 16, 0, 0);
}

// ---------------- lengths ----------------
__global__ void len_kernel(const int* __restrict__ mask, int* __restrict__ lengths) {
  __shared__ int red[256];
  for (int b = 0; b < NB; ++b) {
    int s = 0;
    for (int i = threadIdx.x; i < NN; i += 256) s += mask[b * NN + i];
    red[threadIdx.x] = s;
    __syncthreads();
    for (int off = 128; off > 0; off >>= 1) {
      if (threadIdx.x < off) red[threadIdx.x] += red[threadIdx.x + off];
      __syncthreads();
    }
    if (threadIdx.x == 0) lengths[b] = red[0];
    __syncthreads();
  }
}

// ---------------- R[w,h] ----------------
__global__ void r_kernel(const float* __restrict__ wemb, const float* __restrict__ W1,
                         const float* __restrict__ b1, float* __restrict__ R) {
  int w = blockIdx.x;
  for (int h = threadIdx.x; h < HH; h += 256) {
    float acc = b1[h];
    for (int j = 0; j < 20; ++j)
      acc = fmaf(wemb[w * 20 + j], W1[(size_t)(3 * HH + j) * HH + h], acc);
    R[w * HH + h] = acc;
  }
}

// ---------------- prep Bt: W1c -> single bf16, tiled [hby][ki][col128 x k32] ----------------
__global__ __launch_bounds__(256) void prep_bt_kernel(const float* __restrict__ W1,
                                                      unsigned short* __restrict__ Bt) {
  const int ki = blockIdx.x;   // 0..23
  const int hby = blockIdx.y;  // 0..5
  const float* W1c = W1 + (size_t)(2 * HH) * HH;
  const int t = threadIdx.x;
#pragma unroll
  for (int half = 0; half < 2; ++half) {
    const int c = t + half * 256;          // chunk 0..511
    const int col = c >> 2, kg = c & 3;    // plain tiling (no swizzle; read direct)
    us8 v;
#pragma unroll
    for (int j = 0; j < 8; ++j) {
      const int k = ki * 32 + kg * 8 + j;
      v[j] = f2bf_rn(W1c[(size_t)k * HH + hby * 128 + col]);
    }
    *(us8*)(Bt + ((size_t)(hby * 24 + ki) * 512 + c) * 8) = v;
  }
}

// ---------------- prep At: bf16(x*y), tiled + bank-swizzled [b][tile][ki][row128 x k32] ----------------
__global__ __launch_bounds__(256) void prep_a_kernel(
    const float* __restrict__ emb, const int* __restrict__ spans,
    unsigned short* __restrict__ At, int S, int tileofs) {
  const int tl = blockIdx.x, b = blockIdx.y;
  const int tile = tileofs + tl;
  const int t = threadIdx.x;
#pragma unroll
  for (int half = 0; half < 2; ++half) {
    const int c = t + half * 256;  // chunk 0..511
    const int row = c >> 2, kgs = c & 3;
    const int kg = kgs ^ ((row >> 1) & 3);  // swizzle baked into global image
    int g = tile * 128 + row;
    if (g >= S) g = S - 1;
    const int s = spans[2 * g], e = spans[2 * g + 1];
    const float* xr = emb + ((size_t)b * NN + s) * HH;
    const float* yr = emb + ((size_t)b * NN + e) * HH;
    unsigned short* dst = At + (((size_t)b * CHT + tl) * 24 * 512 + c) * 8;
    for (int ki = 0; ki < 24; ++ki) {
      const int k0 = ki * 32 + kg * 8;
      float4 x0 = *(const float4*)(xr + k0);
      float4 x1 = *(const float4*)(xr + k0 + 4);
      float4 y0 = *(const float4*)(yr + k0);
      float4 y1 = *(const float4*)(yr + k0 + 4);
      us8 v;
      v[0] = f2bf_rn(x0.x * y0.x); v[1] = f2bf_rn(x0.y * y0.y);
      v[2] = f2bf_rn(x0.z * y0.z); v[3] = f2bf_rn(x0.w * y0.w);
      v[4] = f2bf_rn(x1.x * y1.x); v[5] = f2bf_rn(x1.y * y1.y);
      v[6] = f2bf_rn(x1.z * y1.z); v[7] = f2bf_rn(x1.w * y1.w);
      *(us8*)(dst + (size_t)ki * 4096) = v;
    }
  }
}

// ---------------- P/Q (fp32, validated) ----------------
__global__ __launch_bounds__(256) void pq_kernel(
    const float* __restrict__ emb, const float* __restrict__ W1,
    float* __restrict__ P, float* __restrict__ Q) {
  __shared__ float As[KT][ASTR];
  __shared__ float Bs[KT][BSTR];
  const int tile = blockIdx.x;
  const int yb = blockIdx.y;
  const bool isQ = (yb >= 3);
  const int hb = (yb - (isQ ? 3 : 0)) * NT;
  const float* Bbase = W1 + (isQ ? (size_t)HH * HH : 0);
  float* Obase = isQ ? Q : P;
  const int tid = threadIdx.x;
  const int th = tid & 31, tw = tid >> 5;
  const int m0 = tid >> 3, m1 = m0 + 32;
  const int d0 = (tid & 7) << 2;
  const size_t r0 = (size_t)(tile * MT + m0) * HH;
  const size_t r1 = (size_t)(tile * MT + m1) * HH;
  const int bc = (tid & 63) << 2;
  const int br = tid >> 6;
  float acc[8][8];
#pragma unroll
  for (int i = 0; i < 8; ++i)
#pragma unroll
    for (int j = 0; j < 8; ++j) acc[i][j] = 0.f;
  for (int kt = 0; kt < HH; kt += KT) {
    float4 x0 = *reinterpret_cast<const float4*>(emb + r0 + kt + d0);
    float4 x1 = *reinterpret_cast<const float4*>(emb + r1 + kt + d0);
    float4 bw[8];
#pragma unroll
    for (int r = 0; r < 8; ++r)
      bw[r] = *reinterpret_cast<const float4*>(Bbase + (size_t)(kt + br + 4 * r) * HH + hb + bc);
    __syncthreads();
    As[d0 + 0][m0] = x0.x; As[d0 + 1][m0] = x0.y; As[d0 + 2][m0] = x0.z; As[d0 + 3][m0] = x0.w;
    As[d0 + 0][m1] = x1.x; As[d0 + 1][m1] = x1.y; As[d0 + 2][m1] = x1.z; As[d0 + 3][m1] = x1.w;
#pragma unroll
    for (int r = 0; r < 8; ++r)
      *reinterpret_cast<float4*>(&Bs[br + 4 * r][bc]) = bw[r];
    __syncthreads();
#pragma unroll
    for (int d = 0; d < KT; ++d) {
      const float4 a0 = *reinterpret_cast<const float4*>(&As[d][tw * 4]);
      const float4 a1 = *reinterpret_cast<const float4*>(&As[d][tw * 4 + 32]);
      const float4 b0 = *reinterpret_cast<const float4*>(&Bs[d][th * 4]);
      const float4 b1v = *reinterpret_cast<const float4*>(&Bs[d][th * 4 + 128]);
      const float av[8] = {a0.x, a0.y, a0.z, a0.w, a1.x, a1.y, a1.z, a1.w};
      const float bv[8] = {b0.x, b0.y, b0.z, b0.w, b1v.x, b1v.y, b1v.z, b1v.w};
#pragma unroll
      for (int mi = 0; mi < 8; ++mi)
#pragma unroll
        for (int ni = 0; ni < 8; ++ni)
          acc[mi][ni] = fmaf(av[mi], bv[ni], acc[mi][ni]);
    }
  }
#pragma unroll
  for (int mi = 0; mi < 8; ++mi) {
    const int m = tw * 4 + (mi & 3) + ((mi >> 2) << 5);
    float* op = Obase + (size_t)(tile * MT + m) * HH + hb;
    *reinterpret_cast<float4*>(op + th * 4) = make_float4(acc[mi][0], acc[mi][1], acc[mi][2], acc[mi][3]);
    *reinterpret_cast<float4*>(op + th * 4 + 128) = make_float4(acc[mi][4], acc[mi][5], acc[mi][6], acc[mi][7]);
  }
}

// ---------------- MFMA single-bf16 scoring v3 ----------------
__global__ __launch_bounds__(256, 3) void score_mfma3_kernel(
    const int* __restrict__ spans,
    const unsigned short* __restrict__ At, const unsigned short* __restrict__ Bt,
    const float* __restrict__ w_s,
    const float* __restrict__ P, const float* __restrict__ Q, const float* __restrict__ R,
    float* __restrict__ spart, int S, int tileofs) {
  __shared__ unsigned short Asm[128 * 32];
  __shared__ int ssm[128], eem[128], wwm[128];
  __shared__ float sred[128 * 2];

  const int tl = blockIdx.x;
  const int tile = tileofs + tl;
  const int hby = blockIdx.y;
  const int b = blockIdx.z;
  const int tid = threadIdx.x;
  const int lane = tid & 63, w = tid >> 6;
  const int wm = w & 1, wn = w >> 1;
  const int lm = lane & 15, lq = lane >> 4;

  if (tid < 128) {
    int g = tile * 128 + tid;
    int gg = g < S ? g : S - 1;
    int s = spans[2 * gg], e = spans[2 * gg + 1];
    ssm[tid] = s; eem[tid] = e; wwm[tid] = e - s;
  }

  f32x4 acc[4][4];
#pragma unroll
  for (int i = 0; i < 4; ++i)
#pragma unroll
    for (int j = 0; j < 4; ++j) acc[i][j] = (f32x4){0.f, 0.f, 0.f, 0.f};

  const unsigned short* Ab = At + ((size_t)b * CHT + tl) * 24 * 4096;
  const unsigned short* Bb = Bt + (size_t)hby * 24 * 4096;
  // swizzled A fragment address (shorts): row*32 + (lq ^ ((lm>>1)&3))*8, row = wm*64+mi*16+lm
  const int a_off = (wm * 64 + lm) * 32 + (lq ^ ((lm >> 1) & 3)) * 8;
  const int b_off = (wn * 64 + lm) * 32 + lq * 8;

  for (int ki = 0; ki < 24; ++ki) {
    // stage A tile (8 KB) via async global->LDS, 2x16B per thread, lane-linear dest
    async_copy16(Ab + (size_t)ki * 4096 + tid * 8, Asm + tid * 8);
    async_copy16(Ab + (size_t)ki * 4096 + (tid + 256) * 8, Asm + (tid + 256) * 8);
    // B fragments direct from global (L2-resident, coalesced 4KB/wave)
    bf16x8 bfr[4];
#pragma unroll
    for (int ni = 0; ni < 4; ++ni)
      bfr[ni] = *reinterpret_cast<const bf16x8*>(Bb + (size_t)ki * 4096 + b_off + ni * 512);
    __syncthreads();  // drains vmcnt (async copies + b loads)
    bf16x8 afr[4];
#pragma unroll
    for (int mi = 0; mi < 4; ++mi)
      afr[mi] = *reinterpret_cast<const bf16x8*>(Asm + a_off + mi * 512);
#pragma unroll
    for (int ni = 0; ni < 4; ++ni)
#pragma unroll
      for (int mi = 0; mi < 4; ++mi)
        acc[mi][ni] = __builtin_amdgcn_mfma_f32_16x16x32_bf16(afr[mi], bfr[ni], acc[mi][ni], 0, 0, 0);
    __syncthreads();  // protect Asm for next iter
  }

  const int hbg = hby * 128;
  float wsv[4];
#pragma unroll
  for (int ni = 0; ni < 4; ++ni) wsv[ni] = w_s[hbg + wn * 64 + ni * 16 + lm];

#pragma unroll
  for (int mi = 0; mi < 4; ++mi) {
#pragma unroll
    for (int r = 0; r < 4; ++r) {
      const int rowl = wm * 64 + mi * 16 + lq * 4 + r;
      const int s = ssm[rowl], e = eem[rowl], wd = wwm[rowl];
      const float* Pp = P + ((size_t)b * NN + s) * HH + hbg + wn * 64 + lm;
      const float* Qp = Q + ((size_t)b * NN + e) * HH + hbg + wn * 64 + lm;
      const float* Rp = R + (size_t)wd * HH + hbg + wn * 64 + lm;
      float psum = 0.f;
#pragma unroll
      for (int ni = 0; ni < 4; ++ni) {
        float z = acc[mi][ni][r] + Pp[ni * 16] + Qp[ni * 16] + Rp[ni * 16];
        psum = fmaf(gelu_f(z), wsv[ni], psum);
      }
      psum += __shfl_xor(psum, 1);
      psum += __shfl_xor(psum, 2);
      psum += __shfl_xor(psum, 4);
      psum += __shfl_xor(psum, 8);
      if (lm == 0) sred[rowl * 2 + wn] = psum;
    }
  }
  __syncthreads();
  if (tid < 128) {
    int g = tile * 128 + tid;
    if (g < S)
      spart[(size_t)hby * ((size_t)NB * S) + (size_t)b * S + g] = sred[tid * 2] + sred[tid * 2 + 1];
  }
}

// ---------------- combine 6 partials + bias + penalty ----------------
__global__ void combine_kernel(const float* __restrict__ sp, const int* __restrict__ spans,
                               const float* __restrict__ b_s, const int* __restrict__ lengths,
                               float* __restrict__ scores, int S) {
  int idx = blockIdx.x * 256 + threadIdx.x;
  if (idx >= NB * S) return;
  int b = idx / S, i = idx - b * S;
  size_t st = (size_t)NB * S;
  float v = b_s[0];
#pragma unroll
  for (int j = 0; j < 6; ++j) v += sp[j * st + idx];
  if (spans[2 * i + 1] >= lengths[b]) v += -1000000.0f;
  scores[idx] = v;
}

// ---------------- radix pivot + zero band counter ----------------
__global__ __launch_bounds__(1024) void pivot_kernel(const float* __restrict__ scores,
                                                     const int* __restrict__ kptr, int S,
                                                     float* __restrict__ pivotf,
                                                     int* __restrict__ bandcount) {
  const int b = blockIdx.x;
  const int tid = threadIdx.x;
  const float* sc = scores + (size_t)b * S;
  const int k = kptr[0];
  __shared__ unsigned hist[256];
  __shared__ unsigned sh_prefix;
  __shared__ int sh_remaining;
  unsigned prefix = 0;
  int remaining = k;
  for (int round = 0; round < 4; ++round) {
    const int shift = 24 - 8 * round;
    if (tid < 256) hist[tid] = 0;
    __syncthreads();
    for (int i = tid; i < S; i += 1024) {
      unsigned key = f2key(sc[i]);
      if (round == 0 || (key >> (shift + 8)) == prefix)
        atomicAdd(&hist[(key >> shift) & 255u], 1u);
    }
    __syncthreads();
    if (tid == 0) {
      int cum = 0;
      for (int bin = 255; bin >= 0; --bin) {
        int c = (int)hist[bin];
        if (cum + c >= remaining) {
          sh_prefix = (prefix << 8) | (unsigned)bin;
          sh_remaining = remaining - cum;
          break;
        }
        cum += c;
      }
    }
    __syncthreads();
    prefix = sh_prefix;
    remaining = sh_remaining;
    __syncthreads();
  }
  if (tid == 0) {
    pivotf[b] = key2f(prefix);
    bandcount[b] = 0;
  }
}

// ---------------- band collect ----------------
__global__ void band_kernel(const float* __restrict__ scores, const float* __restrict__ pivotf,
                            int* __restrict__ bandcount, int* __restrict__ bandlist, int S) {
  int idx = blockIdx.x * 256 + threadIdx.x;
  if (idx >= NB * S) return;
  int b = idx / S, i = idx - b * S;
  if (fabsf(scores[idx] - pivotf[b]) <= BAND_TAU) {
    int slot = atomicAdd(&bandcount[b], 1);
    if (slot < BANDCAP) bandlist[b * BANDCAP + slot] = i;
  }
}

// ---------------- exact fp32 rescore of band spans ----------------
__global__ __launch_bounds__(256) void rescore_kernel(
    const float* __restrict__ emb, const int* __restrict__ spans,
    const float* __restrict__ W1, const float* __restrict__ w_s,
    const float* __restrict__ b_s, const int* __restrict__ lengths,
    const float* __restrict__ P, const float* __restrict__ Q, const float* __restrict__ R,
    const int* __restrict__ bandcount, const int* __restrict__ bandlist,
    float* __restrict__ scores, int S) {
  const int b = blockIdx.y;
  int cnt = bandcount[b];
  if (cnt > BANDCAP) cnt = BANDCAP;
  if ((int)blockIdx.x >= cnt) return;
  const int i = bandlist[b * BANDCAP + blockIdx.x];
  const int s = spans[2 * i], e = spans[2 * i + 1], wd = e - s;
  const int tid = threadIdx.x;
  __shared__ float prod[HH];
  __shared__ float red[256];
  for (int c = tid; c < HH; c += 256)
    prod[c] = emb[((size_t)b * NN + s) * HH + c] * emb[((size_t)b * NN + e) * HH + c];
  __syncthreads();
  const float* W1c = W1 + (size_t)(2 * HH) * HH;
  float psum = 0.f;
  for (int c0 = 0; c0 < HH; c0 += 256) {
    const int c = c0 + tid;
    float a = P[((size_t)b * NN + s) * HH + c] + Q[((size_t)b * NN + e) * HH + c] + R[(size_t)wd * HH + c];
    for (int k = 0; k < HH; ++k) a = fmaf(prod[k], W1c[(size_t)k * HH + c], a);
    psum = fmaf(gelu_f(a), w_s[c], psum);
  }
  red[tid] = psum;
  __syncthreads();
  for (int off = 128; off > 0; off >>= 1) {
    if (tid < off) red[tid] += red[tid + off];
    __syncthreads();
  }
  if (tid == 0) {
    float v = red[0] + b_s[0];
    if (e >= lengths[b]) v += -1000000.0f;
    scores[(size_t)b * S + i] = v;
  }
}

// ---------------- exact top-k (radix + index-ordered compaction) ----------------
__global__ __launch_bounds__(1024) void topk_kernel(
    const float* __restrict__ scores, const int* __restrict__ spans,
    const int* __restrict__ kptr, int S,
    float* __restrict__ out_spans, int* __restrict__ sel) {
  const int b = blockIdx.x;
  const int tid = threadIdx.x;
  const float* sc = scores + (size_t)b * S;
  const int k = kptr[0];
  __shared__ unsigned hist[256];
  __shared__ unsigned sh_prefix;
  __shared__ int sh_remaining;
  __shared__ int wave_eq[16], wave_sel[16];
  __shared__ int selbase, eqbase;
  unsigned prefix = 0;
  int remaining = k;
  for (int round = 0; round < 4; ++round) {
    const int shift = 24 - 8 * round;
    if (tid < 256) hist[tid] = 0;
    __syncthreads();
    for (int i = tid; i < S; i += 1024) {
      unsigned key = f2key(sc[i]);
      if (round == 0 || (key >> (shift + 8)) == prefix)
        atomicAdd(&hist[(key >> shift) & 255u], 1u);
    }
    __syncthreads();
    if (tid == 0) {
      int cum = 0;
      for (int bin = 255; bin >= 0; --bin) {
        int c = (int)hist[bin];
        if (cum + c >= remaining) {
          sh_prefix = (prefix << 8) | (unsigned)bin;
          sh_remaining = remaining - cum;
          break;
        }
        cum += c;
      }
    }
    __syncthreads();
    prefix = sh_prefix;
    remaining = sh_remaining;
    __syncthreads();
  }
  const unsigned pivot = prefix;
  const int m_eq = remaining;
  if (tid == 0) { selbase = 0; eqbase = 0; }
  __syncthreads();
  const int lane = tid & 63, wv = tid >> 6;
  for (int base = 0; base < S; base += 1024) {
    const int i = base + tid;
    const bool inb = (i < S);
    const unsigned key = inb ? f2key(sc[i]) : 0u;
    const bool gt = inb && (key > pivot);
    const bool eq = inb && (key == pivot);
    unsigned long long mm = __ballot(eq);
    int eqpre = __popcll(mm & ((1ull << lane) - 1ull));
    if (lane == 0) wave_eq[wv] = __popcll(mm);
    __syncthreads();
    int eqpref = 0, eqtot = 0;
#pragma unroll
    for (int w2 = 0; w2 < 16; ++w2) {
      int c = wave_eq[w2];
      if (w2 < wv) eqpref += c;
      eqtot += c;
    }
    const bool take_eq = eq && (eqbase + eqpref + eqpre < m_eq);
    const bool sf = gt || take_eq;
    unsigned long long sm = __ballot(sf);
    int spre = __popcll(sm & ((1ull << lane) - 1ull));
    if (lane == 0) wave_sel[wv] = __popcll(sm);
    __syncthreads();
    int spref = 0, stot = 0;
#pragma unroll
    for (int w2 = 0; w2 < 16; ++w2) {
      int c = wave_sel[w2];
      if (w2 < wv) spref += c;
      stot += c;
    }
    if (sf) {
      const int j = selbase + spref + spre;
      out_spans[(b * KTOP + j) * 2 + 0] = (float)spans[2 * i];
      out_spans[(b * KTOP + j) * 2 + 1] = (float)spans[2 * i + 1];
      sel[b * KTOP + j] = i;
    }
    __syncthreads();
    if (tid == 0) { selbase += stot; eqbase += eqtot; }
    __syncthreads();
  }
}

// ---------------- exact fp32 gather: h embeddings + score partials ----------------
__global__ __launch_bounds__(256) void gather_kernel(
    const float* __restrict__ emb, const int* __restrict__ spans,
    const float* __restrict__ W1, const float* __restrict__ w_s,
    const float* __restrict__ P, const float* __restrict__ Q,
    const float* __restrict__ R, const int* __restrict__ sel,
    float* __restrict__ outh, float* __restrict__ spartg) {
  __shared__ float As[KT][ASTR];
  __shared__ float Bs[KT][BSTR];
  __shared__ int ssm[MT], eem[MT], wwm[MT], vvm[MT];
  const int tile = blockIdx.x;
  const int hb = blockIdx.y * NT;
  const int b = blockIdx.z;
  const int tid = threadIdx.x;
  const int th = tid & 31, tw = tid >> 5;
  if (tid < MT) {
    int s = 0, e = 0, valid = 0;
    int j = tile * MT + tid;
    if (j < KTOP) { int i = sel[b * KTOP + j]; s = spans[2 * i]; e = spans[2 * i + 1]; valid = 1; }
    ssm[tid] = s; eem[tid] = e; wwm[tid] = e - s; vvm[tid] = valid;
  }
  __syncthreads();
  const int m0 = tid >> 3, m1 = m0 + 32;
  const int d0 = (tid & 7) << 2;
  const size_t ebase = (size_t)b * NN * HH;
  const size_t rx0 = ebase + (size_t)ssm[m0] * HH;
  const size_t ry0 = ebase + (size_t)eem[m0] * HH;
  const size_t rx1 = ebase + (size_t)ssm[m1] * HH;
  const size_t ry1 = ebase + (size_t)eem[m1] * HH;
  const float* W1c = W1 + (size_t)(2 * HH) * HH;
  const int bc = (tid & 63) << 2;
  const int br = tid >> 6;
  float acc[8][8];
#pragma unroll
  for (int i = 0; i < 8; ++i)
#pragma unroll
    for (int j = 0; j < 8; ++j) acc[i][j] = 0.f;
  for (int kt = 0; kt < HH; kt += KT) {
    float4 x0 = *reinterpret_cast<const float4*>(emb + rx0 + kt + d0);
    float4 y0 = *reinterpret_cast<const float4*>(emb + ry0 + kt + d0);
    float4 x1 = *reinterpret_cast<const float4*>(emb + rx1 + kt + d0);
    float4 y1 = *reinterpret_cast<const float4*>(emb + ry1 + kt + d0);
    float4 bw[8];
#pragma unroll
    for (int r = 0; r < 8; ++r)
      bw[r] = *reinterpret_cast<const float4*>(W1c + (size_t)(kt + br + 4 * r) * HH + hb + bc);
    __syncthreads();
    As[d0 + 0][m0] = x0.x * y0.x; As[d0 + 1][m0] = x0.y * y0.y;
    As[d0 + 2][m0] = x0.z * y0.z; As[d0 + 3][m0] = x0.w * y0.w;
    As[d0 + 0][m1] = x1.x * y1.x; As[d0 + 1][m1] = x1.y * y1.y;
    As[d0 + 2][m1] = x1.z * y1.z; As[d0 + 3][m1] = x1.w * y1.w;
#pragma unroll
    for (int r = 0; r < 8; ++r)
      *reinterpret_cast<float4*>(&Bs[br + 4 * r][bc]) = bw[r];
    __syncthreads();
#pragma unroll
    for (int d = 0; d < KT; ++d) {
      const float4 a0 = *reinterpret_cast<const float4*>(&As[d][tw * 4]);
      const float4 a1 = *reinterpret_cast<const float4*>(&As[d][tw * 4 + 32]);
      const float4 b0 = *reinterpret_cast<const float4*>(&Bs[d][th * 4]);
      const float4 b1v = *reinterpret_cast<const float4*>(&Bs[d][th * 4 + 128]);
      const float av[8] = {a0.x, a0.y, a0.z, a0.w, a1.x, a1.y, a1.z, a1.w};
      const float bv[8] = {b0.x, b0.y, b0.z, b0.w, b1v.x, b1v.y, b1v.z, b1v.w};
#pragma unroll
      for (int mi = 0; mi < 8; ++mi)
#pragma unroll
        for (int ni = 0; ni < 8; ++ni)
          acc[mi][ni] = fmaf(av[mi], bv[ni], acc[mi][ni]);
    }
  }
  __syncthreads();
  float wv[8];
  {
    const float4 w0 = *reinterpret_cast<const float4*>(w_s + hb + th * 4);
    const float4 w1 = *reinterpret_cast<const float4*>(w_s + hb + th * 4 + 128);
    wv[0] = w0.x; wv[1] = w0.y; wv[2] = w0.z; wv[3] = w0.w;
    wv[4] = w1.x; wv[5] = w1.y; wv[6] = w1.z; wv[7] = w1.w;
  }
  float* sred = (float*)As;
#pragma unroll
  for (int mi = 0; mi < 8; ++mi) {
    const int m = tw * 4 + (mi & 3) + ((mi >> 2) << 5);
    float psum = 0.f;
    if (vvm[m]) {
      const int s = ssm[m], e = eem[m], wd = wwm[m];
      const float* Pp = P + ((size_t)b * NN + s) * HH + hb;
      const float* Qp = Q + ((size_t)b * NN + e) * HH + hb;
      const float* Rp = R + (size_t)wd * HH + hb;
      const float4 p0 = *reinterpret_cast<const float4*>(Pp + th * 4);
      const float4 p1 = *reinterpret_cast<const float4*>(Pp + th * 4 + 128);
      const float4 q0 = *reinterpret_cast<const float4*>(Qp + th * 4);
      const float4 q1 = *reinterpret_cast<const float4*>(Qp + th * 4 + 128);
      const float4 r0 = *reinterpret_cast<const float4*>(Rp + th * 4);
      const float4 r1 = *reinterpret_cast<const float4*>(Rp + th * 4 + 128);
      const float pz[8] = {p0.x + q0.x + r0.x, p0.y + q0.y + r0.y,
                           p0.z + q0.z + r0.z, p0.w + q0.w + r0.w,
                           p1.x + q1.x + r1.x, p1.y + q1.y + r1.y,
                           p1.z + q1.z + r1.z, p1.w + q1.w + r1.w};
      float gl[8];
#pragma unroll
      for (int ni = 0; ni < 8; ++ni) gl[ni] = gelu_f(acc[mi][ni] + pz[ni]);
      const int jj = tile * MT + m;
      float* op = outh + (size_t)(b * KTOP + jj) * HH + hb;
      *reinterpret_cast<float4*>(op + th * 4) = make_float4(gl[0], gl[1], gl[2], gl[3]);
      *reinterpret_cast<float4*>(op + th * 4 + 128) = make_float4(gl[4], gl[5], gl[6], gl[7]);
#pragma unroll
      for (int ni = 0; ni < 8; ++ni) psum = fmaf(gl[ni], wv[ni], psum);
    }
    sred[m * 33 + th] = psum;
  }
  __syncthreads();
  if (tid < MT) {
    float t = 0.f;
#pragma unroll
    for (int j = 0; j < 32; ++j) t += sred[tid * 33 + j];
    const int g = tile * MT + tid;
    if (g < KTOP)
      spartg[(size_t)blockIdx.y * (NB * KTOP) + b * KTOP + g] = t;
  }
}

// ---------------- final scores for selected spans ----------------
__global__ void score_fin_kernel(const float* __restrict__ spartg, const int* __restrict__ sel,
                                 const int* __restrict__ spans, const float* __restrict__ b_s,
                                 const int* __restrict__ lengths, float* __restrict__ out_scores) {
  int idx = blockIdx.x * 256 + threadIdx.x;
  if (idx >= NB * KTOP) return;
  int b = idx / KTOP;
  float v = spartg[idx] + spartg[NB * KTOP + idx] + spartg[2 * NB * KTOP + idx] + b_s[0];
  int i = sel[idx];
  if (spans[2 * i + 1] >= lengths[b]) v += -1000000.0f;
  out_scores[idx] = v;
}

extern "C" void kernel_launch(void* const* d_in, const int* in_sizes, int n_in,
                              void* d_out, int out_size, void* d_ws, size_t ws_size,
                              hipStream_t stream) {
  const float* emb = (const float*)d_in[0];
  const int* mask = (const int*)d_in[1];
  const int* spans = (const int*)d_in[2];
  const float* wemb = (const float*)d_in[3];
  const float* W1 = (const float*)d_in[4];
  const float* b1 = (const float*)d_in[5];
  const float* w_s = (const float*)d_in[6];
  const float* b_s = (const float*)d_in[7];
  const int* kptr = (const int*)d_in[8];
  const int S = in_sizes[2] / 2;  // 30285
  float* out = (float*)d_out;

  char* wp = (char*)d_ws;
  auto take = [&](size_t bytes) {
    char* p = wp;
    wp += (bytes + 63) & ~(size_t)63;
    return p;
  };
  float* Pb = (float*)take((size_t)NB * NN * HH * 4);
  float* Qb = (float*)take((size_t)NB * NN * HH * 4);
  float* Rb = (float*)take((size_t)MAXW * HH * 4);
  float* spart = (float*)take(6 * (size_t)NB * S * 4);
  float* scoresb = (float*)take((size_t)NB * S * 4);
  float* spartg = (float*)take(3 * (size_t)NB * KTOP * 4);
  float* pivotf = (float*)take(NB * 4);
  unsigned short* At = (unsigned short*)take((size_t)NB * CHT * 24 * 4096 * 2);  // 47 MB
  unsigned short* Bt = (unsigned short*)take((size_t)6 * 24 * 4096 * 2);         // 1.2 MB
  int* selb = (int*)take(NB * KTOP * 4);
  int* lengthsb = (int*)take(NB * 4);
  int* bandcount = (int*)take(NB * 4);
  int* bandlist = (int*)take((size_t)NB * BANDCAP * 4);

  const size_t OFF1 = (size_t)NB * KTOP * HH;    // embs
  const size_t OFF2 = OFF1 + (size_t)NB * KTOP;  // scores | spans

  const int tiles = (S + 127) / 128;  // 237

  len_kernel<<<dim3(1), dim3(256), 0, stream>>>(mask, lengthsb);
  r_kernel<<<dim3(MAXW), dim3(256), 0, stream>>>(wemb, W1, b1, Rb);
  prep_bt_kernel<<<dim3(24, 6), dim3(256), 0, stream>>>(W1, Bt);
  pq_kernel<<<dim3((NB * NN) / MT, 6), dim3(256), 0, stream>>>(emb, W1, Pb, Qb);

  // scoring in two tile-chunks to bound At workspace
  for (int pass = 0; pass < 2; ++pass) {
    const int ofs = pass * CHT;
    const int nt = (pass == 0) ? CHT : (tiles - CHT);
    prep_a_kernel<<<dim3(nt, NB), dim3(256), 0, stream>>>(emb, spans, At, S, ofs);
    score_mfma3_kernel<<<dim3(nt, 6, NB), dim3(256), 0, stream>>>(
        spans, At, Bt, w_s, Pb, Qb, Rb, spart, S, ofs);
  }

  combine_kernel<<<dim3((NB * S + 255) / 256), dim3(256), 0, stream>>>(
      spart, spans, b_s, lengthsb, scoresb, S);
  pivot_kernel<<<dim3(NB), dim3(1024), 0, stream>>>(scoresb, kptr, S, pivotf, bandcount);
  band_kernel<<<dim3((NB * S + 255) / 256), dim3(256), 0, stream>>>(
      scoresb, pivotf, bandcount, bandlist, S);
  rescore_kernel<<<dim3(BANDCAP, NB), dim3(256), 0, stream>>>(
      emb, spans, W1, w_s, b_s, lengthsb, Pb, Qb, Rb, bandcount, bandlist, scoresb, S);
  topk_kernel<<<dim3(NB), dim3(1024), 0, stream>>>(scoresb, spans, kptr, S, out + OFF2, selb);
  gather_kernel<<<dim3((KTOP + MT - 1) / MT, 3, NB), dim3(256), 0, stream>>>(
      emb, spans, W1, w_s, Pb, Qb, Rb, selb, out, spartg);
  score_fin_kernel<<<dim3((NB * KTOP + 255) / 256), dim3(256), 0, stream>>>(
      spartg, selb, spans, b_s, lengthsb, out + OFF1);
}

// Round 4
// 716.951 us; speedup vs baseline: 1.2566x; 1.2566x over previous
//
#include <hip/hip_runtime.h>
#include <math.h>

#define NB 2
#define NN 1024
#define HH 768
#define MAXW 30
#define KTOP 409
#define BANDCAP 4096
#define BAND_TAU 2e-2f
#define CHT 120    // tile-chunk stride for At buffer (two passes: 120 + 117)
#define GPAD 448   // 7*64 padded selected-span rows
#define SP416 416  // 26*16 padded rows for spartg slabs

typedef __attribute__((ext_vector_type(4))) float f32x4;
typedef __attribute__((ext_vector_type(8))) __bf16 bf16x8;
typedef __attribute__((ext_vector_type(8))) unsigned short us8;

constexpr int MT = 64, NT = 256, KT = 32;
constexpr int ASTR = MT + 4;
constexpr int BSTR = NT + 4;

__device__ __forceinline__ float gelu_f(float z) {
  return 0.5f * z * (1.0f + erff(z * 0.70710678118654752440f));
}
__device__ __forceinline__ unsigned f2key(float f) {
  unsigned u = __float_as_uint(f);
  return (u & 0x80000000u) ? ~u : (u | 0x80000000u);
}
__device__ __forceinline__ float key2f(unsigned k) {
  unsigned u = (k & 0x80000000u) ? (k & 0x7fffffffu) : ~k;
  return __uint_as_float(u);
}
__device__ __forceinline__ unsigned short f2bf_rn(float f) {
  unsigned u = __float_as_uint(f);
  unsigned r = u + 0x7fffu + ((u >> 16) & 1u);
  return (unsigned short)(r >> 16);
}
__device__ __forceinline__ void async_copy16(const void* g, void* l) {
  __builtin_amdgcn_global_load_lds(
      (const __attribute__((address_space(1))) unsigned int*)g,
      (__attribute__((address_space(3))) unsigned int*)l, 16, 0, 0);
}

// ---------------- lengths ----------------
__global__ void len_kernel(const int* __restrict__ mask, int* __restrict__ lengths) {
  __shared__ int red[256];
  for (int b = 0; b < NB; ++b) {
    int s = 0;
    for (int i = threadIdx.x; i < NN; i += 256) s += mask[b * NN + i];
    red[threadIdx.x] = s;
    __syncthreads();
    for (int off = 128; off > 0; off >>= 1) {
      if (threadIdx.x < off) red[threadIdx.x] += red[threadIdx.x + off];
      __syncthreads();
    }
    if (threadIdx.x == 0) lengths[b] = red[0];
    __syncthreads();
  }
}

// ---------------- R[w,h] ----------------
__global__ void r_kernel(const float* __restrict__ wemb, const float* __restrict__ W1,
                         const float* __restrict__ b1, float* __restrict__ R) {
  int w = blockIdx.x;
  for (int h = threadIdx.x; h < HH; h += 256) {
    float acc = b1[h];
    for (int j = 0; j < 20; ++j)
      acc = fmaf(wemb[w * 20 + j], W1[(size_t)(3 * HH + j) * HH + h], acc);
    R[w * HH + h] = acc;
  }
}

// ---------------- prep Bt ----------------
__global__ __launch_bounds__(256) void prep_bt_kernel(const float* __restrict__ W1,
                                                      unsigned short* __restrict__ Bt) {
  const int ki = blockIdx.x;
  const int hby = blockIdx.y;
  const float* W1c = W1 + (size_t)(2 * HH) * HH;
  const int t = threadIdx.x;
#pragma unroll
  for (int half = 0; half < 2; ++half) {
    const int c = t + half * 256;
    const int col = c >> 2, kg = c & 3;
    us8 v;
#pragma unroll
    for (int j = 0; j < 8; ++j) {
      const int k = ki * 32 + kg * 8 + j;
      v[j] = f2bf_rn(W1c[(size_t)k * HH + hby * 128 + col]);
    }
    *(us8*)(Bt + ((size_t)(hby * 24 + ki) * 512 + c) * 8) = v;
  }
}

// ---------------- prep At: bf16(x*y), tiled + bank-swizzled ----------------
__global__ __launch_bounds__(256) void prep_a_kernel(
    const float* __restrict__ emb, const int* __restrict__ spans,
    unsigned short* __restrict__ At, int S, int tileofs) {
  const int tl = blockIdx.x, b = blockIdx.y;
  const int tile = tileofs + tl;
  const int t = threadIdx.x;
#pragma unroll
  for (int half = 0; half < 2; ++half) {
    const int c = t + half * 256;
    const int row = c >> 2, kgs = c & 3;
    const int kg = kgs ^ ((row >> 1) & 3);
    int g = tile * 128 + row;
    if (g >= S) g = S - 1;
    const int s = spans[2 * g], e = spans[2 * g + 1];
    const float* xr = emb + ((size_t)b * NN + s) * HH;
    const float* yr = emb + ((size_t)b * NN + e) * HH;
    unsigned short* dst = At + (((size_t)b * CHT + tl) * 24 * 512 + c) * 8;
    for (int ki = 0; ki < 24; ++ki) {
      const int k0 = ki * 32 + kg * 8;
      float4 x0 = *(const float4*)(xr + k0);
      float4 x1 = *(const float4*)(xr + k0 + 4);
      float4 y0 = *(const float4*)(yr + k0);
      float4 y1 = *(const float4*)(yr + k0 + 4);
      us8 v;
      v[0] = f2bf_rn(x0.x * y0.x); v[1] = f2bf_rn(x0.y * y0.y);
      v[2] = f2bf_rn(x0.z * y0.z); v[3] = f2bf_rn(x0.w * y0.w);
      v[4] = f2bf_rn(x1.x * y1.x); v[5] = f2bf_rn(x1.y * y1.y);
      v[6] = f2bf_rn(x1.z * y1.z); v[7] = f2bf_rn(x1.w * y1.w);
      *(us8*)(dst + (size_t)ki * 4096) = v;
    }
  }
}

// ---------------- P/Q (fp32, validated) ----------------
__global__ __launch_bounds__(256) void pq_kernel(
    const float* __restrict__ emb, const float* __restrict__ W1,
    float* __restrict__ P, float* __restrict__ Q) {
  __shared__ float As[KT][ASTR];
  __shared__ float Bs[KT][BSTR];
  const int tile = blockIdx.x;
  const int yb = blockIdx.y;
  const bool isQ = (yb >= 3);
  const int hb = (yb - (isQ ? 3 : 0)) * NT;
  const float* Bbase = W1 + (isQ ? (size_t)HH * HH : 0);
  float* Obase = isQ ? Q : P;
  const int tid = threadIdx.x;
  const int th = tid & 31, tw = tid >> 5;
  const int m0 = tid >> 3, m1 = m0 + 32;
  const int d0 = (tid & 7) << 2;
  const size_t r0 = (size_t)(tile * MT + m0) * HH;
  const size_t r1 = (size_t)(tile * MT + m1) * HH;
  const int bc = (tid & 63) << 2;
  const int br = tid >> 6;
  float acc[8][8];
#pragma unroll
  for (int i = 0; i < 8; ++i)
#pragma unroll
    for (int j = 0; j < 8; ++j) acc[i][j] = 0.f;
  for (int kt = 0; kt < HH; kt += KT) {
    float4 x0 = *reinterpret_cast<const float4*>(emb + r0 + kt + d0);
    float4 x1 = *reinterpret_cast<const float4*>(emb + r1 + kt + d0);
    float4 bw[8];
#pragma unroll
    for (int r = 0; r < 8; ++r)
      bw[r] = *reinterpret_cast<const float4*>(Bbase + (size_t)(kt + br + 4 * r) * HH + hb + bc);
    __syncthreads();
    As[d0 + 0][m0] = x0.x; As[d0 + 1][m0] = x0.y; As[d0 + 2][m0] = x0.z; As[d0 + 3][m0] = x0.w;
    As[d0 + 0][m1] = x1.x; As[d0 + 1][m1] = x1.y; As[d0 + 2][m1] = x1.z; As[d0 + 3][m1] = x1.w;
#pragma unroll
    for (int r = 0; r < 8; ++r)
      *reinterpret_cast<float4*>(&Bs[br + 4 * r][bc]) = bw[r];
    __syncthreads();
#pragma unroll
    for (int d = 0; d < KT; ++d) {
      const float4 a0 = *reinterpret_cast<const float4*>(&As[d][tw * 4]);
      const float4 a1 = *reinterpret_cast<const float4*>(&As[d][tw * 4 + 32]);
      const float4 b0 = *reinterpret_cast<const float4*>(&Bs[d][th * 4]);
      const float4 b1v = *reinterpret_cast<const float4*>(&Bs[d][th * 4 + 128]);
      const float av[8] = {a0.x, a0.y, a0.z, a0.w, a1.x, a1.y, a1.z, a1.w};
      const float bv[8] = {b0.x, b0.y, b0.z, b0.w, b1v.x, b1v.y, b1v.z, b1v.w};
#pragma unroll
      for (int mi = 0; mi < 8; ++mi)
#pragma unroll
        for (int ni = 0; ni < 8; ++ni)
          acc[mi][ni] = fmaf(av[mi], bv[ni], acc[mi][ni]);
    }
  }
#pragma unroll
  for (int mi = 0; mi < 8; ++mi) {
    const int m = tw * 4 + (mi & 3) + ((mi >> 2) << 5);
    float* op = Obase + (size_t)(tile * MT + m) * HH + hb;
    *reinterpret_cast<float4*>(op + th * 4) = make_float4(acc[mi][0], acc[mi][1], acc[mi][2], acc[mi][3]);
    *reinterpret_cast<float4*>(op + th * 4 + 128) = make_float4(acc[mi][4], acc[mi][5], acc[mi][6], acc[mi][7]);
  }
}

// ---------------- MFMA single-bf16 scoring v3 ----------------
__global__ __launch_bounds__(256, 3) void score_mfma3_kernel(
    const int* __restrict__ spans,
    const unsigned short* __restrict__ At, const unsigned short* __restrict__ Bt,
    const float* __restrict__ w_s,
    const float* __restrict__ P, const float* __restrict__ Q, const float* __restrict__ R,
    float* __restrict__ spart, int S, int tileofs) {
  __shared__ unsigned short Asm[128 * 32];
  __shared__ int ssm[128], eem[128], wwm[128];
  __shared__ float sred[128 * 2];

  const int tl = blockIdx.x;
  const int tile = tileofs + tl;
  const int hby = blockIdx.y;
  const int b = blockIdx.z;
  const int tid = threadIdx.x;
  const int lane = tid & 63, w = tid >> 6;
  const int wm = w & 1, wn = w >> 1;
  const int lm = lane & 15, lq = lane >> 4;

  if (tid < 128) {
    int g = tile * 128 + tid;
    int gg = g < S ? g : S - 1;
    int s = spans[2 * gg], e = spans[2 * gg + 1];
    ssm[tid] = s; eem[tid] = e; wwm[tid] = e - s;
  }

  f32x4 acc[4][4];
#pragma unroll
  for (int i = 0; i < 4; ++i)
#pragma unroll
    for (int j = 0; j < 4; ++j) acc[i][j] = (f32x4){0.f, 0.f, 0.f, 0.f};

  const unsigned short* Ab = At + ((size_t)b * CHT + tl) * 24 * 4096;
  const unsigned short* Bb = Bt + (size_t)hby * 24 * 4096;
  const int a_off = (wm * 64 + lm) * 32 + (lq ^ ((lm >> 1) & 3)) * 8;
  const int b_off = (wn * 64 + lm) * 32 + lq * 8;

  for (int ki = 0; ki < 24; ++ki) {
    async_copy16(Ab + (size_t)ki * 4096 + tid * 8, Asm + tid * 8);
    async_copy16(Ab + (size_t)ki * 4096 + (tid + 256) * 8, Asm + (tid + 256) * 8);
    bf16x8 bfr[4];
#pragma unroll
    for (int ni = 0; ni < 4; ++ni)
      bfr[ni] = *reinterpret_cast<const bf16x8*>(Bb + (size_t)ki * 4096 + b_off + ni * 512);
    __syncthreads();
    bf16x8 afr[4];
#pragma unroll
    for (int mi = 0; mi < 4; ++mi)
      afr[mi] = *reinterpret_cast<const bf16x8*>(Asm + a_off + mi * 512);
#pragma unroll
    for (int ni = 0; ni < 4; ++ni)
#pragma unroll
      for (int mi = 0; mi < 4; ++mi)
        acc[mi][ni] = __builtin_amdgcn_mfma_f32_16x16x32_bf16(afr[mi], bfr[ni], acc[mi][ni], 0, 0, 0);
    __syncthreads();
  }

  const int hbg = hby * 128;
  float wsv[4];
#pragma unroll
  for (int ni = 0; ni < 4; ++ni) wsv[ni] = w_s[hbg + wn * 64 + ni * 16 + lm];

#pragma unroll
  for (int mi = 0; mi < 4; ++mi) {
#pragma unroll
    for (int r = 0; r < 4; ++r) {
      const int rowl = wm * 64 + mi * 16 + lq * 4 + r;
      const int s = ssm[rowl], e = eem[rowl], wd = wwm[rowl];
      const float* Pp = P + ((size_t)b * NN + s) * HH + hbg + wn * 64 + lm;
      const float* Qp = Q + ((size_t)b * NN + e) * HH + hbg + wn * 64 + lm;
      const float* Rp = R + (size_t)wd * HH + hbg + wn * 64 + lm;
      float psum = 0.f;
#pragma unroll
      for (int ni = 0; ni < 4; ++ni) {
        float z = acc[mi][ni][r] + Pp[ni * 16] + Qp[ni * 16] + Rp[ni * 16];
        psum = fmaf(gelu_f(z), wsv[ni], psum);
      }
      psum += __shfl_xor(psum, 1);
      psum += __shfl_xor(psum, 2);
      psum += __shfl_xor(psum, 4);
      psum += __shfl_xor(psum, 8);
      if (lm == 0) sred[rowl * 2 + wn] = psum;
    }
  }
  __syncthreads();
  if (tid < 128) {
    int g = tile * 128 + tid;
    if (g < S)
      spart[(size_t)hby * ((size_t)NB * S) + (size_t)b * S + g] = sred[tid * 2] + sred[tid * 2 + 1];
  }
}

// ---------------- combine 6 partials + bias + penalty ----------------
__global__ void combine_kernel(const float* __restrict__ sp, const int* __restrict__ spans,
                               const float* __restrict__ b_s, const int* __restrict__ lengths,
                               float* __restrict__ scores, int S) {
  int idx = blockIdx.x * 256 + threadIdx.x;
  if (idx >= NB * S) return;
  int b = idx / S, i = idx - b * S;
  size_t st = (size_t)NB * S;
  float v = b_s[0];
#pragma unroll
  for (int j = 0; j < 6; ++j) v += sp[j * st + idx];
  if (spans[2 * i + 1] >= lengths[b]) v += -1000000.0f;
  scores[idx] = v;
}

// ---------------- radix pivot + zero band counter ----------------
__global__ __launch_bounds__(1024) void pivot_kernel(const float* __restrict__ scores,
                                                     const int* __restrict__ kptr, int S,
                                                     float* __restrict__ pivotf,
                                                     int* __restrict__ bandcount) {
  const int b = blockIdx.x;
  const int tid = threadIdx.x;
  const float* sc = scores + (size_t)b * S;
  const int k = kptr[0];
  __shared__ unsigned hist[256];
  __shared__ unsigned sh_prefix;
  __shared__ int sh_remaining;
  unsigned prefix = 0;
  int remaining = k;
  for (int round = 0; round < 4; ++round) {
    const int shift = 24 - 8 * round;
    if (tid < 256) hist[tid] = 0;
    __syncthreads();
    for (int i = tid; i < S; i += 1024) {
      unsigned key = f2key(sc[i]);
      if (round == 0 || (key >> (shift + 8)) == prefix)
        atomicAdd(&hist[(key >> shift) & 255u], 1u);
    }
    __syncthreads();
    if (tid == 0) {
      int cum = 0;
      for (int bin = 255; bin >= 0; --bin) {
        int c = (int)hist[bin];
        if (cum + c >= remaining) {
          sh_prefix = (prefix << 8) | (unsigned)bin;
          sh_remaining = remaining - cum;
          break;
        }
        cum += c;
      }
    }
    __syncthreads();
    prefix = sh_prefix;
    remaining = sh_remaining;
    __syncthreads();
  }
  if (tid == 0) {
    pivotf[b] = key2f(prefix);
    bandcount[b] = 0;
  }
}

// ---------------- band collect ----------------
__global__ void band_kernel(const float* __restrict__ scores, const float* __restrict__ pivotf,
                            int* __restrict__ bandcount, int* __restrict__ bandlist, int S) {
  int idx = blockIdx.x * 256 + threadIdx.x;
  if (idx >= NB * S) return;
  int b = idx / S, i = idx - b * S;
  if (fabsf(scores[idx] - pivotf[b]) <= BAND_TAU) {
    int slot = atomicAdd(&bandcount[b], 1);
    if (slot < BANDCAP) bandlist[b * BANDCAP + slot] = i;
  }
}

// ---------------- exact fp32 rescore of band spans ----------------
__global__ __launch_bounds__(256) void rescore_kernel(
    const float* __restrict__ emb, const int* __restrict__ spans,
    const float* __restrict__ W1, const float* __restrict__ w_s,
    const float* __restrict__ b_s, const int* __restrict__ lengths,
    const float* __restrict__ P, const float* __restrict__ Q, const float* __restrict__ R,
    const int* __restrict__ bandcount, const int* __restrict__ bandlist,
    float* __restrict__ scores, int S) {
  const int b = blockIdx.y;
  int cnt = bandcount[b];
  if (cnt > BANDCAP) cnt = BANDCAP;
  if ((int)blockIdx.x >= cnt) return;
  const int i = bandlist[b * BANDCAP + blockIdx.x];
  const int s = spans[2 * i], e = spans[2 * i + 1], wd = e - s;
  const int tid = threadIdx.x;
  __shared__ float prod[HH];
  __shared__ float red[256];
  for (int c = tid; c < HH; c += 256)
    prod[c] = emb[((size_t)b * NN + s) * HH + c] * emb[((size_t)b * NN + e) * HH + c];
  __syncthreads();
  const float* W1c = W1 + (size_t)(2 * HH) * HH;
  float psum = 0.f;
  for (int c0 = 0; c0 < HH; c0 += 256) {
    const int c = c0 + tid;
    float a = P[((size_t)b * NN + s) * HH + c] + Q[((size_t)b * NN + e) * HH + c] + R[(size_t)wd * HH + c];
    for (int k = 0; k < HH; ++k) a = fmaf(prod[k], W1c[(size_t)k * HH + c], a);
    psum = fmaf(gelu_f(a), w_s[c], psum);
  }
  red[tid] = psum;
  __syncthreads();
  for (int off = 128; off > 0; off >>= 1) {
    if (tid < off) red[tid] += red[tid + off];
    __syncthreads();
  }
  if (tid == 0) {
    float v = red[0] + b_s[0];
    if (e >= lengths[b]) v += -1000000.0f;
    scores[(size_t)b * S + i] = v;
  }
}

// ---------------- exact top-k (radix + index-ordered compaction) ----------------
__global__ __launch_bounds__(1024) void topk_kernel(
    const float* __restrict__ scores, const int* __restrict__ spans,
    const int* __restrict__ kptr, int S,
    float* __restrict__ out_spans, int* __restrict__ sel) {
  const int b = blockIdx.x;
  const int tid = threadIdx.x;
  const float* sc = scores + (size_t)b * S;
  const int k = kptr[0];
  __shared__ unsigned hist[256];
  __shared__ unsigned sh_prefix;
  __shared__ int sh_remaining;
  __shared__ int wave_eq[16], wave_sel[16];
  __shared__ int selbase, eqbase;
  unsigned prefix = 0;
  int remaining = k;
  for (int round = 0; round < 4; ++round) {
    const int shift = 24 - 8 * round;
    if (tid < 256) hist[tid] = 0;
    __syncthreads();
    for (int i = tid; i < S; i += 1024) {
      unsigned key = f2key(sc[i]);
      if (round == 0 || (key >> (shift + 8)) == prefix)
        atomicAdd(&hist[(key >> shift) & 255u], 1u);
    }
    __syncthreads();
    if (tid == 0) {
      int cum = 0;
      for (int bin = 255; bin >= 0; --bin) {
        int c = (int)hist[bin];
        if (cum + c >= remaining) {
          sh_prefix = (prefix << 8) | (unsigned)bin;
          sh_remaining = remaining - cum;
          break;
        }
        cum += c;
      }
    }
    __syncthreads();
    prefix = sh_prefix;
    remaining = sh_remaining;
    __syncthreads();
  }
  const unsigned pivot = prefix;
  const int m_eq = remaining;
  if (tid == 0) { selbase = 0; eqbase = 0; }
  __syncthreads();
  const int lane = tid & 63, wv = tid >> 6;
  for (int base = 0; base < S; base += 1024) {
    const int i = base + tid;
    const bool inb = (i < S);
    const unsigned key = inb ? f2key(sc[i]) : 0u;
    const bool gt = inb && (key > pivot);
    const bool eq = inb && (key == pivot);
    unsigned long long mm = __ballot(eq);
    int eqpre = __popcll(mm & ((1ull << lane) - 1ull));
    if (lane == 0) wave_eq[wv] = __popcll(mm);
    __syncthreads();
    int eqpref = 0, eqtot = 0;
#pragma unroll
    for (int w2 = 0; w2 < 16; ++w2) {
      int c = wave_eq[w2];
      if (w2 < wv) eqpref += c;
      eqtot += c;
    }
    const bool take_eq = eq && (eqbase + eqpref + eqpre < m_eq);
    const bool sf = gt || take_eq;
    unsigned long long sm = __ballot(sf);
    int spre = __popcll(sm & ((1ull << lane) - 1ull));
    if (lane == 0) wave_sel[wv] = __popcll(sm);
    __syncthreads();
    int spref = 0, stot = 0;
#pragma unroll
    for (int w2 = 0; w2 < 16; ++w2) {
      int c = wave_sel[w2];
      if (w2 < wv) spref += c;
      stot += c;
    }
    if (sf) {
      const int j = selbase + spref + spre;
      out_spans[(b * KTOP + j) * 2 + 0] = (float)spans[2 * i];
      out_spans[(b * KTOP + j) * 2 + 1] = (float)spans[2 * i + 1];
      sel[b * KTOP + j] = i;
    }
    __syncthreads();
    if (tid == 0) { selbase += stot; eqbase += eqtot; }
    __syncthreads();
  }
}

// ---------------- gather part: fp32 (x*y)@W1c partial over K-chunk of 128 ----------------
__global__ __launch_bounds__(256) void gather_part_kernel(
    const float* __restrict__ emb, const int* __restrict__ spans,
    const float* __restrict__ W1, const int* __restrict__ sel,
    float* __restrict__ Gpart) {
  __shared__ float As[KT][ASTR];
  __shared__ float Bs[KT][BSTR];
  __shared__ int ssm[MT], eem[MT];
  const int tile = blockIdx.x;          // 0..6
  const int hby6 = blockIdx.y;          // 0..17
  const int hb = (hby6 / 6) * NT;
  const int ks = hby6 % 6;              // K chunk
  const int b = blockIdx.z;
  const int tid = threadIdx.x;
  const int th = tid & 31, tw = tid >> 5;
  if (tid < MT) {
    int j = tile * MT + tid;
    if (j >= KTOP) j = KTOP - 1;
    int i = sel[b * KTOP + j];
    ssm[tid] = spans[2 * i];
    eem[tid] = spans[2 * i + 1];
  }
  __syncthreads();
  const int m0 = tid >> 3, m1 = m0 + 32;
  const int d0 = (tid & 7) << 2;
  const size_t ebase = (size_t)b * NN * HH;
  const size_t rx0 = ebase + (size_t)ssm[m0] * HH;
  const size_t ry0 = ebase + (size_t)eem[m0] * HH;
  const size_t rx1 = ebase + (size_t)ssm[m1] * HH;
  const size_t ry1 = ebase + (size_t)eem[m1] * HH;
  const float* W1c = W1 + (size_t)(2 * HH) * HH;
  const int bc = (tid & 63) << 2;
  const int br = tid >> 6;
  float acc[8][8];
#pragma unroll
  for (int i = 0; i < 8; ++i)
#pragma unroll
    for (int j = 0; j < 8; ++j) acc[i][j] = 0.f;
  const int k0 = ks * 128;
  for (int it = 0; it < 4; ++it) {
    const int kt = k0 + it * KT;
    float4 x0 = *reinterpret_cast<const float4*>(emb + rx0 + kt + d0);
    float4 y0 = *reinterpret_cast<const float4*>(emb + ry0 + kt + d0);
    float4 x1 = *reinterpret_cast<const float4*>(emb + rx1 + kt + d0);
    float4 y1 = *reinterpret_cast<const float4*>(emb + ry1 + kt + d0);
    float4 bw[8];
#pragma unroll
    for (int r = 0; r < 8; ++r)
      bw[r] = *reinterpret_cast<const float4*>(W1c + (size_t)(kt + br + 4 * r) * HH + hb + bc);
    __syncthreads();
    As[d0 + 0][m0] = x0.x * y0.x; As[d0 + 1][m0] = x0.y * y0.y;
    As[d0 + 2][m0] = x0.z * y0.z; As[d0 + 3][m0] = x0.w * y0.w;
    As[d0 + 0][m1] = x1.x * y1.x; As[d0 + 1][m1] = x1.y * y1.y;
    As[d0 + 2][m1] = x1.z * y1.z; As[d0 + 3][m1] = x1.w * y1.w;
#pragma unroll
    for (int r = 0; r < 8; ++r)
      *reinterpret_cast<float4*>(&Bs[br + 4 * r][bc]) = bw[r];
    __syncthreads();
#pragma unroll
    for (int d = 0; d < KT; ++d) {
      const float4 a0 = *reinterpret_cast<const float4*>(&As[d][tw * 4]);
      const float4 a1 = *reinterpret_cast<const float4*>(&As[d][tw * 4 + 32]);
      const float4 b0 = *reinterpret_cast<const float4*>(&Bs[d][th * 4]);
      const float4 b1v = *reinterpret_cast<const float4*>(&Bs[d][th * 4 + 128]);
      const float av[8] = {a0.x, a0.y, a0.z, a0.w, a1.x, a1.y, a1.z, a1.w};
      const float bv[8] = {b0.x, b0.y, b0.z, b0.w, b1v.x, b1v.y, b1v.z, b1v.w};
#pragma unroll
      for (int mi = 0; mi < 8; ++mi)
#pragma unroll
        for (int ni = 0; ni < 8; ++ni)
          acc[mi][ni] = fmaf(av[mi], bv[ni], acc[mi][ni]);
    }
  }
#pragma unroll
  for (int mi = 0; mi < 8; ++mi) {
    const int m = tw * 4 + (mi & 3) + ((mi >> 2) << 5);
    float* op = Gpart + (((size_t)ks * NB + b) * GPAD + tile * MT + m) * HH + hb;
    *reinterpret_cast<float4*>(op + th * 4) = make_float4(acc[mi][0], acc[mi][1], acc[mi][2], acc[mi][3]);
    *reinterpret_cast<float4*>(op + th * 4 + 128) = make_float4(acc[mi][4], acc[mi][5], acc[mi][6], acc[mi][7]);
  }
}

// ---------------- gather fin: sum partials + PQR -> gelu -> h + score partials ----------------
__global__ __launch_bounds__(256) void gather_fin_kernel(
    const float* __restrict__ Gpart, const int* __restrict__ spans,
    const int* __restrict__ sel,
    const float* __restrict__ P, const float* __restrict__ Q, const float* __restrict__ R,
    const float* __restrict__ w_s, float* __restrict__ outh, float* __restrict__ spartg) {
  __shared__ int ssm[16], eem[16], wwm[16], vvm[16];
  __shared__ float sred[16];
  const int t16 = blockIdx.x;   // 0..25
  const int hby = blockIdx.y;   // 0..5
  const int b = blockIdx.z;
  const int tid = threadIdx.x;
  if (tid < 16) {
    int j = t16 * 16 + tid;
    int valid = (j < KTOP) ? 1 : 0;
    int jj = valid ? j : KTOP - 1;
    int i = sel[b * KTOP + jj];
    ssm[tid] = spans[2 * i];
    eem[tid] = spans[2 * i + 1];
    wwm[tid] = eem[tid] - ssm[tid];
    vvm[tid] = valid;
  }
  __syncthreads();
  const int row = tid >> 4;        // 0..15
  const int cc = tid & 15;         // col chunk
  const int g448 = t16 * 16 + row; // < 416
  const int co = hby * 128 + cc * 8;
  float v[8];
#pragma unroll
  for (int i = 0; i < 8; ++i) v[i] = 0.f;
#pragma unroll
  for (int ks = 0; ks < 6; ++ks) {
    const float* gp = Gpart + (((size_t)ks * NB + b) * GPAD + g448) * HH + co;
    float4 a = *(const float4*)gp;
    float4 c = *(const float4*)(gp + 4);
    v[0] += a.x; v[1] += a.y; v[2] += a.z; v[3] += a.w;
    v[4] += c.x; v[5] += c.y; v[6] += c.z; v[7] += c.w;
  }
  const int s = ssm[row], e = eem[row], wd = wwm[row];
  const float* Pp = P + ((size_t)b * NN + s) * HH + co;
  const float* Qp = Q + ((size_t)b * NN + e) * HH + co;
  const float* Rp = R + (size_t)wd * HH + co;
  float4 p0 = *(const float4*)Pp, p1 = *(const float4*)(Pp + 4);
  float4 q0 = *(const float4*)Qp, q1 = *(const float4*)(Qp + 4);
  float4 r0 = *(const float4*)Rp, r1 = *(const float4*)(Rp + 4);
  v[0] += p0.x + q0.x + r0.x; v[1] += p0.y + q0.y + r0.y;
  v[2] += p0.z + q0.z + r0.z; v[3] += p0.w + q0.w + r0.w;
  v[4] += p1.x + q1.x + r1.x; v[5] += p1.y + q1.y + r1.y;
  v[6] += p1.z + q1.z + r1.z; v[7] += p1.w + q1.w + r1.w;
  float gl[8];
#pragma unroll
  for (int i = 0; i < 8; ++i) gl[i] = gelu_f(v[i]);
  float psum = 0.f;
  if (vvm[row]) {
    const int j = t16 * 16 + row;
    float* op = outh + (size_t)(b * KTOP + j) * HH + co;
    *(float4*)op = make_float4(gl[0], gl[1], gl[2], gl[3]);
    *(float4*)(op + 4) = make_float4(gl[4], gl[5], gl[6], gl[7]);
    const float4 w0 = *(const float4*)(w_s + co);
    const float4 w1 = *(const float4*)(w_s + co + 4);
    psum = gl[0] * w0.x + gl[1] * w0.y + gl[2] * w0.z + gl[3] * w0.w +
           gl[4] * w1.x + gl[5] * w1.y + gl[6] * w1.z + gl[7] * w1.w;
  }
  psum += __shfl_xor(psum, 1);
  psum += __shfl_xor(psum, 2);
  psum += __shfl_xor(psum, 4);
  psum += __shfl_xor(psum, 8);
  const int lane = tid & 63, wv = tid >> 6;
  if ((lane & 15) == 0) sred[wv * 4 + (lane >> 4)] = psum;
  __syncthreads();
  if (tid < 16)
    spartg[(size_t)hby * (NB * SP416) + b * SP416 + t16 * 16 + tid] = sred[tid];
}

// ---------------- final scores for selected spans ----------------
__global__ void score_fin_kernel(const float* __restrict__ spartg, const int* __restrict__ sel,
                                 const int* __restrict__ spans, const float* __restrict__ b_s,
                                 const int* __restrict__ lengths, float* __restrict__ out_scores) {
  int idx = blockIdx.x * 256 + threadIdx.x;
  if (idx >= NB * KTOP) return;
  int b = idx / KTOP, j = idx - b * KTOP;
  float v = b_s[0];
#pragma unroll
  for (int hby = 0; hby < 6; ++hby)
    v += spartg[(size_t)hby * (NB * SP416) + b * SP416 + j];
  int i = sel[idx];
  if (spans[2 * i + 1] >= lengths[b]) v += -1000000.0f;
  out_scores[idx] = v;
}

extern "C" void kernel_launch(void* const* d_in, const int* in_sizes, int n_in,
                              void* d_out, int out_size, void* d_ws, size_t ws_size,
                              hipStream_t stream) {
  const float* emb = (const float*)d_in[0];
  const int* mask = (const int*)d_in[1];
  const int* spans = (const int*)d_in[2];
  const float* wemb = (const float*)d_in[3];
  const float* W1 = (const float*)d_in[4];
  const float* b1 = (const float*)d_in[5];
  const float* w_s = (const float*)d_in[6];
  const float* b_s = (const float*)d_in[7];
  const int* kptr = (const int*)d_in[8];
  const int S = in_sizes[2] / 2;  // 30285
  float* out = (float*)d_out;

  char* wp = (char*)d_ws;
  auto take = [&](size_t bytes) {
    char* p = wp;
    wp += (bytes + 63) & ~(size_t)63;
    return p;
  };
  float* Pb = (float*)take((size_t)NB * NN * HH * 4);
  float* Qb = (float*)take((size_t)NB * NN * HH * 4);
  float* Rb = (float*)take((size_t)MAXW * HH * 4);
  float* spart = (float*)take(6 * (size_t)NB * S * 4);
  float* scoresb = (float*)take((size_t)NB * S * 4);
  float* spartg = (float*)take(6 * (size_t)NB * SP416 * 4);
  float* Gpart = (float*)take(6 * (size_t)NB * GPAD * HH * 4);  // 16.5 MB
  float* pivotf = (float*)take(NB * 4);
  unsigned short* At = (unsigned short*)take((size_t)NB * CHT * 24 * 4096 * 2);  // 47 MB
  unsigned short* Bt = (unsigned short*)take((size_t)6 * 24 * 4096 * 2);
  int* selb = (int*)take(NB * KTOP * 4);
  int* lengthsb = (int*)take(NB * 4);
  int* bandcount = (int*)take(NB * 4);
  int* bandlist = (int*)take((size_t)NB * BANDCAP * 4);

  const size_t OFF1 = (size_t)NB * KTOP * HH;    // embs
  const size_t OFF2 = OFF1 + (size_t)NB * KTOP;  // scores | spans

  const int tiles = (S + 127) / 128;  // 237

  len_kernel<<<dim3(1), dim3(256), 0, stream>>>(mask, lengthsb);
  r_kernel<<<dim3(MAXW), dim3(256), 0, stream>>>(wemb, W1, b1, Rb);
  prep_bt_kernel<<<dim3(24, 6), dim3(256), 0, stream>>>(W1, Bt);
  pq_kernel<<<dim3((NB * NN) / MT, 6), dim3(256), 0, stream>>>(emb, W1, Pb, Qb);

  for (int pass = 0; pass < 2; ++pass) {
    const int ofs = pass * CHT;
    const int nt = (pass == 0) ? CHT : (tiles - CHT);
    prep_a_kernel<<<dim3(nt, NB), dim3(256), 0, stream>>>(emb, spans, At, S, ofs);
    score_mfma3_kernel<<<dim3(nt, 6, NB), dim3(256), 0, stream>>>(
        spans, At, Bt, w_s, Pb, Qb, Rb, spart, S, ofs);
  }

  combine_kernel<<<dim3((NB * S + 255) / 256), dim3(256), 0, stream>>>(
      spart, spans, b_s, lengthsb, scoresb, S);
  pivot_kernel<<<dim3(NB), dim3(1024), 0, stream>>>(scoresb, kptr, S, pivotf, bandcount);
  band_kernel<<<dim3((NB * S + 255) / 256), dim3(256), 0, stream>>>(
      scoresb, pivotf, bandcount, bandlist, S);
  rescore_kernel<<<dim3(BANDCAP, NB), dim3(256), 0, stream>>>(
      emb, spans, W1, w_s, b_s, lengthsb, Pb, Qb, Rb, bandcount, bandlist, scoresb, S);
  topk_kernel<<<dim3(NB), dim3(1024), 0, stream>>>(scoresb, spans, kptr, S, out + OFF2, selb);
  gather_part_kernel<<<dim3(7, 18, NB), dim3(256), 0, stream>>>(emb, spans, W1, selb, Gpart);
  gather_fin_kernel<<<dim3(26, 6, NB), dim3(256), 0, stream>>>(
      Gpart, spans, selb, Pb, Qb, Rb, w_s, out, spartg);
  score_fin_kernel<<<dim3((NB * KTOP + 255) / 256), dim3(256), 0, stream>>>(
      spartg, selb, spans, b_s, lengthsb, out + OFF1);
}

// Round 5
// 698.700 us; speedup vs baseline: 1.2895x; 1.0261x over previous
//
#include <hip/hip_runtime.h>
#include <math.h>

#define NB 2
#define NN 1024
#define HH 768
#define MAXW 30
#define KTOP 409
#define BANDCAP 4096
#define BAND_TAU 2e-2f
#define CHT 120    // tile-chunk stride for At buffer (two passes: 120 + 117)
#define GPAD 448   // 7*64 padded selected-span rows
#define SP416 416  // 26*16 padded rows for spartg slabs

typedef __attribute__((ext_vector_type(4))) float f32x4;
typedef __attribute__((ext_vector_type(8))) __bf16 bf16x8;
typedef __attribute__((ext_vector_type(8))) unsigned short us8;

constexpr int MT = 64, NT = 256, KT = 32;
constexpr int ASTR = MT + 4;
constexpr int BSTR = NT + 4;

__device__ __forceinline__ float gelu_f(float z) {
  return 0.5f * z * (1.0f + erff(z * 0.70710678118654752440f));
}
__device__ __forceinline__ unsigned f2key(float f) {
  unsigned u = __float_as_uint(f);
  return (u & 0x80000000u) ? ~u : (u | 0x80000000u);
}
__device__ __forceinline__ float key2f(unsigned k) {
  unsigned u = (k & 0x80000000u) ? (k & 0x7fffffffu) : ~k;
  return __uint_as_float(u);
}
__device__ __forceinline__ unsigned short f2bf_rn(float f) {
  unsigned u = __float_as_uint(f);
  unsigned r = u + 0x7fffu + ((u >> 16) & 1u);
  return (unsigned short)(r >> 16);
}
__device__ __forceinline__ void async_copy16(const void* g, void* l) {
  __builtin_amdgcn_global_load_lds(
      (const __attribute__((address_space(1))) unsigned int*)g,
      (__attribute__((address_space(3))) unsigned int*)l, 16, 0, 0);
}

// ---------------- lengths ----------------
__global__ void len_kernel(const int* __restrict__ mask, int* __restrict__ lengths) {
  __shared__ int red[256];
  for (int b = 0; b < NB; ++b) {
    int s = 0;
    for (int i = threadIdx.x; i < NN; i += 256) s += mask[b * NN + i];
    red[threadIdx.x] = s;
    __syncthreads();
    for (int off = 128; off > 0; off >>= 1) {
      if (threadIdx.x < off) red[threadIdx.x] += red[threadIdx.x + off];
      __syncthreads();
    }
    if (threadIdx.x == 0) lengths[b] = red[0];
    __syncthreads();
  }
}

// ---------------- R[w,h] ----------------
__global__ void r_kernel(const float* __restrict__ wemb, const float* __restrict__ W1,
                         const float* __restrict__ b1, float* __restrict__ R) {
  int w = blockIdx.x;
  for (int h = threadIdx.x; h < HH; h += 256) {
    float acc = b1[h];
    for (int j = 0; j < 20; ++j)
      acc = fmaf(wemb[w * 20 + j], W1[(size_t)(3 * HH + j) * HH + h], acc);
    R[w * HH + h] = acc;
  }
}

// ---------------- prep Bt ----------------
__global__ __launch_bounds__(256) void prep_bt_kernel(const float* __restrict__ W1,
                                                      unsigned short* __restrict__ Bt) {
  const int ki = blockIdx.x;
  const int hby = blockIdx.y;
  const float* W1c = W1 + (size_t)(2 * HH) * HH;
  const int t = threadIdx.x;
#pragma unroll
  for (int half = 0; half < 2; ++half) {
    const int c = t + half * 256;
    const int col = c >> 2, kg = c & 3;
    us8 v;
#pragma unroll
    for (int j = 0; j < 8; ++j) {
      const int k = ki * 32 + kg * 8 + j;
      v[j] = f2bf_rn(W1c[(size_t)k * HH + hby * 128 + col]);
    }
    *(us8*)(Bt + ((size_t)(hby * 24 + ki) * 512 + c) * 8) = v;
  }
}

// ---------------- prep At: bf16(x*y), tiled + bank-swizzled ----------------
__global__ __launch_bounds__(256) void prep_a_kernel(
    const float* __restrict__ emb, const int* __restrict__ spans,
    unsigned short* __restrict__ At, int S, int tileofs) {
  const int tl = blockIdx.x, b = blockIdx.y;
  const int tile = tileofs + tl;
  const int t = threadIdx.x;
#pragma unroll
  for (int half = 0; half < 2; ++half) {
    const int c = t + half * 256;
    const int row = c >> 2, kgs = c & 3;
    const int kg = kgs ^ ((row >> 1) & 3);
    int g = tile * 128 + row;
    if (g >= S) g = S - 1;
    const int s = spans[2 * g], e = spans[2 * g + 1];
    const float* xr = emb + ((size_t)b * NN + s) * HH;
    const float* yr = emb + ((size_t)b * NN + e) * HH;
    unsigned short* dst = At + (((size_t)b * CHT + tl) * 24 * 512 + c) * 8;
    for (int ki = 0; ki < 24; ++ki) {
      const int k0 = ki * 32 + kg * 8;
      float4 x0 = *(const float4*)(xr + k0);
      float4 x1 = *(const float4*)(xr + k0 + 4);
      float4 y0 = *(const float4*)(yr + k0);
      float4 y1 = *(const float4*)(yr + k0 + 4);
      us8 v;
      v[0] = f2bf_rn(x0.x * y0.x); v[1] = f2bf_rn(x0.y * y0.y);
      v[2] = f2bf_rn(x0.z * y0.z); v[3] = f2bf_rn(x0.w * y0.w);
      v[4] = f2bf_rn(x1.x * y1.x); v[5] = f2bf_rn(x1.y * y1.y);
      v[6] = f2bf_rn(x1.z * y1.z); v[7] = f2bf_rn(x1.w * y1.w);
      *(us8*)(dst + (size_t)ki * 4096) = v;
    }
  }
}

// ---------------- P/Q part: fp32 GEMM over K-chunk of 256, partials to slab ----------------
__global__ __launch_bounds__(256) void pq_part_kernel(
    const float* __restrict__ emb, const float* __restrict__ W1,
    float* __restrict__ PQpart) {
  __shared__ float As[KT][ASTR];
  __shared__ float Bs[KT][BSTR];
  const int tile = blockIdx.x;
  const int yb = blockIdx.y;
  const int ks = blockIdx.z;  // 0..2, K chunk of 256
  const bool isQ = (yb >= 3);
  const int hb = (yb - (isQ ? 3 : 0)) * NT;
  const float* Bbase = W1 + (isQ ? (size_t)HH * HH : 0);
  const int tid = threadIdx.x;
  const int th = tid & 31, tw = tid >> 5;
  const int m0 = tid >> 3, m1 = m0 + 32;
  const int d0 = (tid & 7) << 2;
  const size_t r0 = (size_t)(tile * MT + m0) * HH;
  const size_t r1 = (size_t)(tile * MT + m1) * HH;
  const int bc = (tid & 63) << 2;
  const int br = tid >> 6;
  float acc[8][8];
#pragma unroll
  for (int i = 0; i < 8; ++i)
#pragma unroll
    for (int j = 0; j < 8; ++j) acc[i][j] = 0.f;
  const int kbeg = ks * 256;
  for (int it = 0; it < 8; ++it) {
    const int kt = kbeg + it * KT;
    float4 x0 = *reinterpret_cast<const float4*>(emb + r0 + kt + d0);
    float4 x1 = *reinterpret_cast<const float4*>(emb + r1 + kt + d0);
    float4 bw[8];
#pragma unroll
    for (int r = 0; r < 8; ++r)
      bw[r] = *reinterpret_cast<const float4*>(Bbase + (size_t)(kt + br + 4 * r) * HH + hb + bc);
    __syncthreads();
    As[d0 + 0][m0] = x0.x; As[d0 + 1][m0] = x0.y; As[d0 + 2][m0] = x0.z; As[d0 + 3][m0] = x0.w;
    As[d0 + 0][m1] = x1.x; As[d0 + 1][m1] = x1.y; As[d0 + 2][m1] = x1.z; As[d0 + 3][m1] = x1.w;
#pragma unroll
    for (int r = 0; r < 8; ++r)
      *reinterpret_cast<float4*>(&Bs[br + 4 * r][bc]) = bw[r];
    __syncthreads();
#pragma unroll
    for (int d = 0; d < KT; ++d) {
      const float4 a0 = *reinterpret_cast<const float4*>(&As[d][tw * 4]);
      const float4 a1 = *reinterpret_cast<const float4*>(&As[d][tw * 4 + 32]);
      const float4 b0 = *reinterpret_cast<const float4*>(&Bs[d][th * 4]);
      const float4 b1v = *reinterpret_cast<const float4*>(&Bs[d][th * 4 + 128]);
      const float av[8] = {a0.x, a0.y, a0.z, a0.w, a1.x, a1.y, a1.z, a1.w};
      const float bv[8] = {b0.x, b0.y, b0.z, b0.w, b1v.x, b1v.y, b1v.z, b1v.w};
#pragma unroll
      for (int mi = 0; mi < 8; ++mi)
#pragma unroll
        for (int ni = 0; ni < 8; ++ni)
          acc[mi][ni] = fmaf(av[mi], bv[ni], acc[mi][ni]);
    }
  }
  const int colg = (isQ ? 768 : 0) + hb;
#pragma unroll
  for (int mi = 0; mi < 8; ++mi) {
    const int m = tw * 4 + (mi & 3) + ((mi >> 2) << 5);
    float* op = PQpart + ((size_t)ks * 2048 + tile * MT + m) * 1536 + colg;
    *reinterpret_cast<float4*>(op + th * 4) = make_float4(acc[mi][0], acc[mi][1], acc[mi][2], acc[mi][3]);
    *reinterpret_cast<float4*>(op + th * 4 + 128) = make_float4(acc[mi][4], acc[mi][5], acc[mi][6], acc[mi][7]);
  }
}

// ---------------- P/Q fin: sum 3 K-chunk slabs -> P, Q ----------------
__global__ __launch_bounds__(256) void pq_fin_kernel(const float* __restrict__ PQpart,
                                                     float* __restrict__ P,
                                                     float* __restrict__ Q) {
  const size_t q = (size_t)blockIdx.x * 256 + threadIdx.x;  // float4 index, < 786432
  const size_t row = q / 384;
  const int col4 = (int)(q - row * 384);
  const int col = col4 * 4;
  const float4* s0 = (const float4*)(PQpart + row * 1536 + col);
  const float4* s1 = (const float4*)(PQpart + (2048 + row) * 1536 + col);
  const float4* s2 = (const float4*)(PQpart + (4096 + row) * 1536 + col);
  float4 a = *s0, b = *s1, c = *s2;
  float4 v = make_float4(a.x + b.x + c.x, a.y + b.y + c.y, a.z + b.z + c.z, a.w + b.w + c.w);
  if (col < 768)
    *(float4*)(P + row * HH + col) = v;
  else
    *(float4*)(Q + row * HH + (col - 768)) = v;
}

// ---------------- MFMA single-bf16 scoring v3 ----------------
__global__ __launch_bounds__(256, 3) void score_mfma3_kernel(
    const int* __restrict__ spans,
    const unsigned short* __restrict__ At, const unsigned short* __restrict__ Bt,
    const float* __restrict__ w_s,
    const float* __restrict__ P, const float* __restrict__ Q, const float* __restrict__ R,
    float* __restrict__ spart, int S, int tileofs) {
  __shared__ unsigned short Asm[128 * 32];
  __shared__ int ssm[128], eem[128], wwm[128];
  __shared__ float sred[128 * 2];

  const int tl = blockIdx.x;
  const int tile = tileofs + tl;
  const int hby = blockIdx.y;
  const int b = blockIdx.z;
  const int tid = threadIdx.x;
  const int lane = tid & 63, w = tid >> 6;
  const int wm = w & 1, wn = w >> 1;
  const int lm = lane & 15, lq = lane >> 4;

  if (tid < 128) {
    int g = tile * 128 + tid;
    int gg = g < S ? g : S - 1;
    int s = spans[2 * gg], e = spans[2 * gg + 1];
    ssm[tid] = s; eem[tid] = e; wwm[tid] = e - s;
  }

  f32x4 acc[4][4];
#pragma unroll
  for (int i = 0; i < 4; ++i)
#pragma unroll
    for (int j = 0; j < 4; ++j) acc[i][j] = (f32x4){0.f, 0.f, 0.f, 0.f};

  const unsigned short* Ab = At + ((size_t)b * CHT + tl) * 24 * 4096;
  const unsigned short* Bb = Bt + (size_t)hby * 24 * 4096;
  const int a_off = (wm * 64 + lm) * 32 + (lq ^ ((lm >> 1) & 3)) * 8;
  const int b_off = (wn * 64 + lm) * 32 + lq * 8;

  for (int ki = 0; ki < 24; ++ki) {
    async_copy16(Ab + (size_t)ki * 4096 + tid * 8, Asm + tid * 8);
    async_copy16(Ab + (size_t)ki * 4096 + (tid + 256) * 8, Asm + (tid + 256) * 8);
    bf16x8 bfr[4];
#pragma unroll
    for (int ni = 0; ni < 4; ++ni)
      bfr[ni] = *reinterpret_cast<const bf16x8*>(Bb + (size_t)ki * 4096 + b_off + ni * 512);
    __syncthreads();
    bf16x8 afr[4];
#pragma unroll
    for (int mi = 0; mi < 4; ++mi)
      afr[mi] = *reinterpret_cast<const bf16x8*>(Asm + a_off + mi * 512);
#pragma unroll
    for (int ni = 0; ni < 4; ++ni)
#pragma unroll
      for (int mi = 0; mi < 4; ++mi)
        acc[mi][ni] = __builtin_amdgcn_mfma_f32_16x16x32_bf16(afr[mi], bfr[ni], acc[mi][ni], 0, 0, 0);
    __syncthreads();
  }

  const int hbg = hby * 128;
  float wsv[4];
#pragma unroll
  for (int ni = 0; ni < 4; ++ni) wsv[ni] = w_s[hbg + wn * 64 + ni * 16 + lm];

#pragma unroll
  for (int mi = 0; mi < 4; ++mi) {
#pragma unroll
    for (int r = 0; r < 4; ++r) {
      const int rowl = wm * 64 + mi * 16 + lq * 4 + r;
      const int s = ssm[rowl], e = eem[rowl], wd = wwm[rowl];
      const float* Pp = P + ((size_t)b * NN + s) * HH + hbg + wn * 64 + lm;
      const float* Qp = Q + ((size_t)b * NN + e) * HH + hbg + wn * 64 + lm;
      const float* Rp = R + (size_t)wd * HH + hbg + wn * 64 + lm;
      float psum = 0.f;
#pragma unroll
      for (int ni = 0; ni < 4; ++ni) {
        float z = acc[mi][ni][r] + Pp[ni * 16] + Qp[ni * 16] + Rp[ni * 16];
        psum = fmaf(gelu_f(z), wsv[ni], psum);
      }
      psum += __shfl_xor(psum, 1);
      psum += __shfl_xor(psum, 2);
      psum += __shfl_xor(psum, 4);
      psum += __shfl_xor(psum, 8);
      if (lm == 0) sred[rowl * 2 + wn] = psum;
    }
  }
  __syncthreads();
  if (tid < 128) {
    int g = tile * 128 + tid;
    if (g < S)
      spart[(size_t)hby * ((size_t)NB * S) + (size_t)b * S + g] = sred[tid * 2] + sred[tid * 2 + 1];
  }
}

// ---------------- combine 6 partials + bias + penalty ----------------
__global__ void combine_kernel(const float* __restrict__ sp, const int* __restrict__ spans,
                               const float* __restrict__ b_s, const int* __restrict__ lengths,
                               float* __restrict__ scores, int S) {
  int idx = blockIdx.x * 256 + threadIdx.x;
  if (idx >= NB * S) return;
  int b = idx / S, i = idx - b * S;
  size_t st = (size_t)NB * S;
  float v = b_s[0];
#pragma unroll
  for (int j = 0; j < 6; ++j) v += sp[j * st + idx];
  if (spans[2 * i + 1] >= lengths[b]) v += -1000000.0f;
  scores[idx] = v;
}

// ---------------- radix pivot + zero band counter ----------------
__global__ __launch_bounds__(1024) void pivot_kernel(const float* __restrict__ scores,
                                                     const int* __restrict__ kptr, int S,
                                                     float* __restrict__ pivotf,
                                                     int* __restrict__ bandcount) {
  const int b = blockIdx.x;
  const int tid = threadIdx.x;
  const float* sc = scores + (size_t)b * S;
  const int k = kptr[0];
  __shared__ unsigned hist[256];
  __shared__ unsigned sh_prefix;
  __shared__ int sh_remaining;
  unsigned prefix = 0;
  int remaining = k;
  for (int round = 0; round < 4; ++round) {
    const int shift = 24 - 8 * round;
    if (tid < 256) hist[tid] = 0;
    __syncthreads();
    for (int i = tid; i < S; i += 1024) {
      unsigned key = f2key(sc[i]);
      if (round == 0 || (key >> (shift + 8)) == prefix)
        atomicAdd(&hist[(key >> shift) & 255u], 1u);
    }
    __syncthreads();
    if (tid == 0) {
      int cum = 0;
      for (int bin = 255; bin >= 0; --bin) {
        int c = (int)hist[bin];
        if (cum + c >= remaining) {
          sh_prefix = (prefix << 8) | (unsigned)bin;
          sh_remaining = remaining - cum;
          break;
        }
        cum += c;
      }
    }
    __syncthreads();
    prefix = sh_prefix;
    remaining = sh_remaining;
    __syncthreads();
  }
  if (tid == 0) {
    pivotf[b] = key2f(prefix);
    bandcount[b] = 0;
  }
}

// ---------------- band collect ----------------
__global__ void band_kernel(const float* __restrict__ scores, const float* __restrict__ pivotf,
                            int* __restrict__ bandcount, int* __restrict__ bandlist, int S) {
  int idx = blockIdx.x * 256 + threadIdx.x;
  if (idx >= NB * S) return;
  int b = idx / S, i = idx - b * S;
  if (fabsf(scores[idx] - pivotf[b]) <= BAND_TAU) {
    int slot = atomicAdd(&bandcount[b], 1);
    if (slot < BANDCAP) bandlist[b * BANDCAP + slot] = i;
  }
}

// ---------------- exact fp32 rescore of band spans ----------------
__global__ __launch_bounds__(256) void rescore_kernel(
    const float* __restrict__ emb, const int* __restrict__ spans,
    const float* __restrict__ W1, const float* __restrict__ w_s,
    const float* __restrict__ b_s, const int* __restrict__ lengths,
    const float* __restrict__ P, const float* __restrict__ Q, const float* __restrict__ R,
    const int* __restrict__ bandcount, const int* __restrict__ bandlist,
    float* __restrict__ scores, int S) {
  const int b = blockIdx.y;
  int cnt = bandcount[b];
  if (cnt > BANDCAP) cnt = BANDCAP;
  if ((int)blockIdx.x >= cnt) return;
  const int i = bandlist[b * BANDCAP + blockIdx.x];
  const int s = spans[2 * i], e = spans[2 * i + 1], wd = e - s;
  const int tid = threadIdx.x;
  __shared__ float prod[HH];
  __shared__ float red[256];
  for (int c = tid; c < HH; c += 256)
    prod[c] = emb[((size_t)b * NN + s) * HH + c] * emb[((size_t)b * NN + e) * HH + c];
  __syncthreads();
  const float* W1c = W1 + (size_t)(2 * HH) * HH;
  float psum = 0.f;
  for (int c0 = 0; c0 < HH; c0 += 256) {
    const int c = c0 + tid;
    float a = P[((size_t)b * NN + s) * HH + c] + Q[((size_t)b * NN + e) * HH + c] + R[(size_t)wd * HH + c];
    for (int k = 0; k < HH; ++k) a = fmaf(prod[k], W1c[(size_t)k * HH + c], a);
    psum = fmaf(gelu_f(a), w_s[c], psum);
  }
  red[tid] = psum;
  __syncthreads();
  for (int off = 128; off > 0; off >>= 1) {
    if (tid < off) red[tid] += red[tid + off];
    __syncthreads();
  }
  if (tid == 0) {
    float v = red[0] + b_s[0];
    if (e >= lengths[b]) v += -1000000.0f;
    scores[(size_t)b * S + i] = v;
  }
}

// ---------------- exact top-k (radix + index-ordered compaction) ----------------
__global__ __launch_bounds__(1024) void topk_kernel(
    const float* __restrict__ scores, const int* __restrict__ spans,
    const int* __restrict__ kptr, int S,
    float* __restrict__ out_spans, int* __restrict__ sel) {
  const int b = blockIdx.x;
  const int tid = threadIdx.x;
  const float* sc = scores + (size_t)b * S;
  const int k = kptr[0];
  __shared__ unsigned hist[256];
  __shared__ unsigned sh_prefix;
  __shared__ int sh_remaining;
  __shared__ int wave_eq[16], wave_sel[16];
  __shared__ int selbase, eqbase;
  unsigned prefix = 0;
  int remaining = k;
  for (int round = 0; round < 4; ++round) {
    const int shift = 24 - 8 * round;
    if (tid < 256) hist[tid] = 0;
    __syncthreads();
    for (int i = tid; i < S; i += 1024) {
      unsigned key = f2key(sc[i]);
      if (round == 0 || (key >> (shift + 8)) == prefix)
        atomicAdd(&hist[(key >> shift) & 255u], 1u);
    }
    __syncthreads();
    if (tid == 0) {
      int cum = 0;
      for (int bin = 255; bin >= 0; --bin) {
        int c = (int)hist[bin];
        if (cum + c >= remaining) {
          sh_prefix = (prefix << 8) | (unsigned)bin;
          sh_remaining = remaining - cum;
          break;
        }
        cum += c;
      }
    }
    __syncthreads();
    prefix = sh_prefix;
    remaining = sh_remaining;
    __syncthreads();
  }
  const unsigned pivot = prefix;
  const int m_eq = remaining;
  if (tid == 0) { selbase = 0; eqbase = 0; }
  __syncthreads();
  const int lane = tid & 63, wv = tid >> 6;
  for (int base = 0; base < S; base += 1024) {
    const int i = base + tid;
    const bool inb = (i < S);
    const unsigned key = inb ? f2key(sc[i]) : 0u;
    const bool gt = inb && (key > pivot);
    const bool eq = inb && (key == pivot);
    unsigned long long mm = __ballot(eq);
    int eqpre = __popcll(mm & ((1ull << lane) - 1ull));
    if (lane == 0) wave_eq[wv] = __popcll(mm);
    __syncthreads();
    int eqpref = 0, eqtot = 0;
#pragma unroll
    for (int w2 = 0; w2 < 16; ++w2) {
      int c = wave_eq[w2];
      if (w2 < wv) eqpref += c;
      eqtot += c;
    }
    const bool take_eq = eq && (eqbase + eqpref + eqpre < m_eq);
    const bool sf = gt || take_eq;
    unsigned long long sm = __ballot(sf);
    int spre = __popcll(sm & ((1ull << lane) - 1ull));
    if (lane == 0) wave_sel[wv] = __popcll(sm);
    __syncthreads();
    int spref = 0, stot = 0;
#pragma unroll
    for (int w2 = 0; w2 < 16; ++w2) {
      int c = wave_sel[w2];
      if (w2 < wv) spref += c;
      stot += c;
    }
    if (sf) {
      const int j = selbase + spref + spre;
      out_spans[(b * KTOP + j) * 2 + 0] = (float)spans[2 * i];
      out_spans[(b * KTOP + j) * 2 + 1] = (float)spans[2 * i + 1];
      sel[b * KTOP + j] = i;
    }
    __syncthreads();
    if (tid == 0) { selbase += stot; eqbase += eqtot; }
    __syncthreads();
  }
}

// ---------------- gather part: fp32 (x*y)@W1c partial over K-chunk of 128 ----------------
__global__ __launch_bounds__(256) void gather_part_kernel(
    const float* __restrict__ emb, const int* __restrict__ spans,
    const float* __restrict__ W1, const int* __restrict__ sel,
    float* __restrict__ Gpart) {
  __shared__ float As[KT][ASTR];
  __shared__ float Bs[KT][BSTR];
  __shared__ int ssm[MT], eem[MT];
  const int tile = blockIdx.x;          // 0..6
  const int hby6 = blockIdx.y;          // 0..17
  const int hb = (hby6 / 6) * NT;
  const int ks = hby6 % 6;              // K chunk
  const int b = blockIdx.z;
  const int tid = threadIdx.x;
  const int th = tid & 31, tw = tid >> 5;
  if (tid < MT) {
    int j = tile * MT + tid;
    if (j >= KTOP) j = KTOP - 1;
    int i = sel[b * KTOP + j];
    ssm[tid] = spans[2 * i];
    eem[tid] = spans[2 * i + 1];
  }
  __syncthreads();
  const int m0 = tid >> 3, m1 = m0 + 32;
  const int d0 = (tid & 7) << 2;
  const size_t ebase = (size_t)b * NN * HH;
  const size_t rx0 = ebase + (size_t)ssm[m0] * HH;
  const size_t ry0 = ebase + (size_t)eem[m0] * HH;
  const size_t rx1 = ebase + (size_t)ssm[m1] * HH;
  const size_t ry1 = ebase + (size_t)eem[m1] * HH;
  const float* W1c = W1 + (size_t)(2 * HH) * HH;
  const int bc = (tid & 63) << 2;
  const int br = tid >> 6;
  float acc[8][8];
#pragma unroll
  for (int i = 0; i < 8; ++i)
#pragma unroll
    for (int j = 0; j < 8; ++j) acc[i][j] = 0.f;
  const int k0 = ks * 128;
  for (int it = 0; it < 4; ++it) {
    const int kt = k0 + it * KT;
    float4 x0 = *reinterpret_cast<const float4*>(emb + rx0 + kt + d0);
    float4 y0 = *reinterpret_cast<const float4*>(emb + ry0 + kt + d0);
    float4 x1 = *reinterpret_cast<const float4*>(emb + rx1 + kt + d0);
    float4 y1 = *reinterpret_cast<const float4*>(emb + ry1 + kt + d0);
    float4 bw[8];
#pragma unroll
    for (int r = 0; r < 8; ++r)
      bw[r] = *reinterpret_cast<const float4*>(W1c + (size_t)(kt + br + 4 * r) * HH + hb + bc);
    __syncthreads();
    As[d0 + 0][m0] = x0.x * y0.x; As[d0 + 1][m0] = x0.y * y0.y;
    As[d0 + 2][m0] = x0.z * y0.z; As[d0 + 3][m0] = x0.w * y0.w;
    As[d0 + 0][m1] = x1.x * y1.x; As[d0 + 1][m1] = x1.y * y1.y;
    As[d0 + 2][m1] = x1.z * y1.z; As[d0 + 3][m1] = x1.w * y1.w;
#pragma unroll
    for (int r = 0; r < 8; ++r)
      *reinterpret_cast<float4*>(&Bs[br + 4 * r][bc]) = bw[r];
    __syncthreads();
#pragma unroll
    for (int d = 0; d < KT; ++d) {
      const float4 a0 = *reinterpret_cast<const float4*>(&As[d][tw * 4]);
      const float4 a1 = *reinterpret_cast<const float4*>(&As[d][tw * 4 + 32]);
      const float4 b0 = *reinterpret_cast<const float4*>(&Bs[d][th * 4]);
      const float4 b1v = *reinterpret_cast<const float4*>(&Bs[d][th * 4 + 128]);
      const float av[8] = {a0.x, a0.y, a0.z, a0.w, a1.x, a1.y, a1.z, a1.w};
      const float bv[8] = {b0.x, b0.y, b0.z, b0.w, b1v.x, b1v.y, b1v.z, b1v.w};
#pragma unroll
      for (int mi = 0; mi < 8; ++mi)
#pragma unroll
        for (int ni = 0; ni < 8; ++ni)
          acc[mi][ni] = fmaf(av[mi], bv[ni], acc[mi][ni]);
    }
  }
#pragma unroll
  for (int mi = 0; mi < 8; ++mi) {
    const int m = tw * 4 + (mi & 3) + ((mi >> 2) << 5);
    float* op = Gpart + (((size_t)ks * NB + b) * GPAD + tile * MT + m) * HH + hb;
    *reinterpret_cast<float4*>(op + th * 4) = make_float4(acc[mi][0], acc[mi][1], acc[mi][2], acc[mi][3]);
    *reinterpret_cast<float4*>(op + th * 4 + 128) = make_float4(acc[mi][4], acc[mi][5], acc[mi][6], acc[mi][7]);
  }
}

// ---------------- gather fin: sum partials + PQR -> gelu -> h + score partials ----------------
__global__ __launch_bounds__(256) void gather_fin_kernel(
    const float* __restrict__ Gpart, const int* __restrict__ spans,
    const int* __restrict__ sel,
    const float* __restrict__ P, const float* __restrict__ Q, const float* __restrict__ R,
    const float* __restrict__ w_s, float* __restrict__ outh, float* __restrict__ spartg) {
  __shared__ int ssm[16], eem[16], wwm[16], vvm[16];
  __shared__ float sred[16];
  const int t16 = blockIdx.x;   // 0..25
  const int hby = blockIdx.y;   // 0..5
  const int b = blockIdx.z;
  const int tid = threadIdx.x;
  if (tid < 16) {
    int j = t16 * 16 + tid;
    int valid = (j < KTOP) ? 1 : 0;
    int jj = valid ? j : KTOP - 1;
    int i = sel[b * KTOP + jj];
    ssm[tid] = spans[2 * i];
    eem[tid] = spans[2 * i + 1];
    wwm[tid] = eem[tid] - ssm[tid];
    vvm[tid] = valid;
  }
  __syncthreads();
  const int row = tid >> 4;
  const int cc = tid & 15;
  const int g448 = t16 * 16 + row;
  const int co = hby * 128 + cc * 8;
  float v[8];
#pragma unroll
  for (int i = 0; i < 8; ++i) v[i] = 0.f;
#pragma unroll
  for (int ks = 0; ks < 6; ++ks) {
    const float* gp = Gpart + (((size_t)ks * NB + b) * GPAD + g448) * HH + co;
    float4 a = *(const float4*)gp;
    float4 c = *(const float4*)(gp + 4);
    v[0] += a.x; v[1] += a.y; v[2] += a.z; v[3] += a.w;
    v[4] += c.x; v[5] += c.y; v[6] += c.z; v[7] += c.w;
  }
  const int s = ssm[row], e = eem[row], wd = wwm[row];
  const float* Pp = P + ((size_t)b * NN + s) * HH + co;
  const float* Qp = Q + ((size_t)b * NN + e) * HH + co;
  const float* Rp = R + (size_t)wd * HH + co;
  float4 p0 = *(const float4*)Pp, p1 = *(const float4*)(Pp + 4);
  float4 q0 = *(const float4*)Qp, q1 = *(const float4*)(Qp + 4);
  float4 r0 = *(const float4*)Rp, r1 = *(const float4*)(Rp + 4);
  v[0] += p0.x + q0.x + r0.x; v[1] += p0.y + q0.y + r0.y;
  v[2] += p0.z + q0.z + r0.z; v[3] += p0.w + q0.w + r0.w;
  v[4] += p1.x + q1.x + r1.x; v[5] += p1.y + q1.y + r1.y;
  v[6] += p1.z + q1.z + r1.z; v[7] += p1.w + q1.w + r1.w;
  float gl[8];
#pragma unroll
  for (int i = 0; i < 8; ++i) gl[i] = gelu_f(v[i]);
  float psum = 0.f;
  if (vvm[row]) {
    const int j = t16 * 16 + row;
    float* op = outh + (size_t)(b * KTOP + j) * HH + co;
    *(float4*)op = make_float4(gl[0], gl[1], gl[2], gl[3]);
    *(float4*)(op + 4) = make_float4(gl[4], gl[5], gl[6], gl[7]);
    const float4 w0 = *(const float4*)(w_s + co);
    const float4 w1 = *(const float4*)(w_s + co + 4);
    psum = gl[0] * w0.x + gl[1] * w0.y + gl[2] * w0.z + gl[3] * w0.w +
           gl[4] * w1.x + gl[5] * w1.y + gl[6] * w1.z + gl[7] * w1.w;
  }
  psum += __shfl_xor(psum, 1);
  psum += __shfl_xor(psum, 2);
  psum += __shfl_xor(psum, 4);
  psum += __shfl_xor(psum, 8);
  const int lane = tid & 63, wv = tid >> 6;
  if ((lane & 15) == 0) sred[wv * 4 + (lane >> 4)] = psum;
  __syncthreads();
  if (tid < 16)
    spartg[(size_t)hby * (NB * SP416) + b * SP416 + t16 * 16 + tid] = sred[tid];
}

// ---------------- final scores for selected spans ----------------
__global__ void score_fin_kernel(const float* __restrict__ spartg, const int* __restrict__ sel,
                                 const int* __restrict__ spans, const float* __restrict__ b_s,
                                 const int* __restrict__ lengths, float* __restrict__ out_scores) {
  int idx = blockIdx.x * 256 + threadIdx.x;
  if (idx >= NB * KTOP) return;
  int b = idx / KTOP, j = idx - b * KTOP;
  float v = b_s[0];
#pragma unroll
  for (int hby = 0; hby < 6; ++hby)
    v += spartg[(size_t)hby * (NB * SP416) + b * SP416 + j];
  int i = sel[idx];
  if (spans[2 * i + 1] >= lengths[b]) v += -1000000.0f;
  out_scores[idx] = v;
}

extern "C" void kernel_launch(void* const* d_in, const int* in_sizes, int n_in,
                              void* d_out, int out_size, void* d_ws, size_t ws_size,
                              hipStream_t stream) {
  const float* emb = (const float*)d_in[0];
  const int* mask = (const int*)d_in[1];
  const int* spans = (const int*)d_in[2];
  const float* wemb = (const float*)d_in[3];
  const float* W1 = (const float*)d_in[4];
  const float* b1 = (const float*)d_in[5];
  const float* w_s = (const float*)d_in[6];
  const float* b_s = (const float*)d_in[7];
  const int* kptr = (const int*)d_in[8];
  const int S = in_sizes[2] / 2;  // 30285
  float* out = (float*)d_out;

  char* wp = (char*)d_ws;
  auto take = [&](size_t bytes) {
    char* p = wp;
    wp += (bytes + 63) & ~(size_t)63;
    return p;
  };
  float* Pb = (float*)take((size_t)NB * NN * HH * 4);
  float* Qb = (float*)take((size_t)NB * NN * HH * 4);
  float* Rb = (float*)take((size_t)MAXW * HH * 4);
  float* spart = (float*)take(6 * (size_t)NB * S * 4);
  float* scoresb = (float*)take((size_t)NB * S * 4);
  float* spartg = (float*)take(6 * (size_t)NB * SP416 * 4);
  float* Gpart = (float*)take(6 * (size_t)NB * GPAD * HH * 4);  // 16.5 MB
  float* pivotf = (float*)take(NB * 4);
  unsigned short* At = (unsigned short*)take((size_t)NB * CHT * 24 * 4096 * 2);  // 47 MB
  unsigned short* Bt = (unsigned short*)take((size_t)6 * 24 * 4096 * 2);
  int* selb = (int*)take(NB * KTOP * 4);
  int* lengthsb = (int*)take(NB * 4);
  int* bandcount = (int*)take(NB * 4);
  int* bandlist = (int*)take((size_t)NB * BANDCAP * 4);

  // PQ partials (3 x 2048 x 1536 fp32 = 37.7 MB) alias the At buffer:
  // pq_part/pq_fin complete before prep_a first writes At (stream-ordered).
  float* PQpart = (float*)At;

  const size_t OFF1 = (size_t)NB * KTOP * HH;    // embs
  const size_t OFF2 = OFF1 + (size_t)NB * KTOP;  // scores | spans

  const int tiles = (S + 127) / 128;  // 237

  len_kernel<<<dim3(1), dim3(256), 0, stream>>>(mask, lengthsb);
  r_kernel<<<dim3(MAXW), dim3(256), 0, stream>>>(wemb, W1, b1, Rb);
  prep_bt_kernel<<<dim3(24, 6), dim3(256), 0, stream>>>(W1, Bt);
  pq_part_kernel<<<dim3((NB * NN) / MT, 6, 3), dim3(256), 0, stream>>>(emb, W1, PQpart);
  pq_fin_kernel<<<dim3(3072), dim3(256), 0, stream>>>(PQpart, Pb, Qb);

  for (int pass = 0; pass < 2; ++pass) {
    const int ofs = pass * CHT;
    const int nt = (pass == 0) ? CHT : (tiles - CHT);
    prep_a_kernel<<<dim3(nt, NB), dim3(256), 0, stream>>>(emb, spans, At, S, ofs);
    score_mfma3_kernel<<<dim3(nt, 6, NB), dim3(256), 0, stream>>>(
        spans, At, Bt, w_s, Pb, Qb, Rb, spart, S, ofs);
  }

  combine_kernel<<<dim3((NB * S + 255) / 256), dim3(256), 0, stream>>>(
      spart, spans, b_s, lengthsb, scoresb, S);
  pivot_kernel<<<dim3(NB), dim3(1024), 0, stream>>>(scoresb, kptr, S, pivotf, bandcount);
  band_kernel<<<dim3((NB * S + 255) / 256), dim3(256), 0, stream>>>(
      scoresb, pivotf, bandcount, bandlist, S);
  rescore_kernel<<<dim3(BANDCAP, NB), dim3(256), 0, stream>>>(
      emb, spans, W1, w_s, b_s, lengthsb, Pb, Qb, Rb, bandcount, bandlist, scoresb, S);
  topk_kernel<<<dim3(NB), dim3(1024), 0, stream>>>(scoresb, spans, kptr, S, out + OFF2, selb);
  gather_part_kernel<<<dim3(7, 18, NB), dim3(256), 0, stream>>>(emb, spans, W1, selb, Gpart);
  gather_fin_kernel<<<dim3(26, 6, NB), dim3(256), 0, stream>>>(
      Gpart, spans, selb, Pb, Qb, Rb, w_s, out, spartg);
  score_fin_kernel<<<dim3((NB * KTOP + 255) / 256), dim3(256), 0, stream>>>(
      spartg, selb, spans, b_s, lengthsb, out + OFF1);
}

// Round 6
// 636.187 us; speedup vs baseline: 1.4162x; 1.0983x over previous
//
#include <hip/hip_runtime.h>
#include <math.h>

#define NB 2
#define NN 1024
#define HH 768
#define MAXW 30
#define KTOP 409
#define BANDCAP 4096
#define BAND_TAU 2e-2f
#define CHT 120    // tile-chunk stride for At buffer (two passes: 120 + 117)
#define GPAD 448   // 7*64 padded selected-span rows
#define SP416 416  // 26*16 padded rows for spartg slabs

typedef __attribute__((ext_vector_type(4))) float f32x4;
typedef __attribute__((ext_vector_type(8))) __bf16 bf16x8;
typedef __attribute__((ext_vector_type(8))) unsigned short us8;

constexpr int MT = 64, NT = 256, KT = 32;
constexpr int ASTR = MT + 4;
constexpr int BSTR = NT + 4;

__device__ __forceinline__ float gelu_f(float z) {
  return 0.5f * z * (1.0f + erff(z * 0.70710678118654752440f));
}
__device__ __forceinline__ unsigned f2key(float f) {
  unsigned u = __float_as_uint(f);
  return (u & 0x80000000u) ? ~u : (u | 0x80000000u);
}
__device__ __forceinline__ float key2f(unsigned k) {
  unsigned u = (k & 0x80000000u) ? (k & 0x7fffffffu) : ~k;
  return __uint_as_float(u);
}
__device__ __forceinline__ unsigned short f2bf_rn(float f) {
  unsigned u = __float_as_uint(f);
  unsigned r = u + 0x7fffu + ((u >> 16) & 1u);
  return (unsigned short)(r >> 16);
}
__device__ __forceinline__ float bf2f(unsigned short h) {
  return __uint_as_float(((unsigned)h) << 16);
}
__device__ __forceinline__ void async_copy16(const void* g, void* l) {
  __builtin_amdgcn_global_load_lds(
      (const __attribute__((address_space(1))) unsigned int*)g,
      (__attribute__((address_space(3))) unsigned int*)l, 16, 0, 0);
}

// ---------------- lengths ----------------
__global__ void len_kernel(const int* __restrict__ mask, int* __restrict__ lengths) {
  __shared__ int red[256];
  for (int b = 0; b < NB; ++b) {
    int s = 0;
    for (int i = threadIdx.x; i < NN; i += 256) s += mask[b * NN + i];
    red[threadIdx.x] = s;
    __syncthreads();
    for (int off = 128; off > 0; off >>= 1) {
      if (threadIdx.x < off) red[threadIdx.x] += red[threadIdx.x + off];
      __syncthreads();
    }
    if (threadIdx.x == 0) lengths[b] = red[0];
    __syncthreads();
  }
}

// ---------------- R[w,h] ----------------
__global__ void r_kernel(const float* __restrict__ wemb, const float* __restrict__ W1,
                         const float* __restrict__ b1, float* __restrict__ R) {
  int w = blockIdx.x;
  for (int h = threadIdx.x; h < HH; h += 256) {
    float acc = b1[h];
    for (int j = 0; j < 20; ++j)
      acc = fmaf(wemb[w * 20 + j], W1[(size_t)(3 * HH + j) * HH + h], acc);
    R[w * HH + h] = acc;
  }
}

// ---------------- prep Bt (W1c single-bf16, for approx scoring) ----------------
__global__ __launch_bounds__(256) void prep_bt_kernel(const float* __restrict__ W1,
                                                      unsigned short* __restrict__ Bt) {
  const int ki = blockIdx.x;
  const int hby = blockIdx.y;
  const float* W1c = W1 + (size_t)(2 * HH) * HH;
  const int t = threadIdx.x;
#pragma unroll
  for (int half = 0; half < 2; ++half) {
    const int c = t + half * 256;
    const int col = c >> 2, kg = c & 3;
    us8 v;
#pragma unroll
    for (int j = 0; j < 8; ++j) {
      const int k = ki * 32 + kg * 8 + j;
      v[j] = f2bf_rn(W1c[(size_t)k * HH + hby * 128 + col]);
    }
    *(us8*)(Bt + ((size_t)(hby * 24 + ki) * 512 + c) * 8) = v;
  }
}

// ---------------- prep emb hi/lo images (swizzled, for pq_mfma A) ----------------
__global__ __launch_bounds__(256) void prep_emb_hl_kernel(
    const float* __restrict__ emb, unsigned short* __restrict__ Ahi,
    unsigned short* __restrict__ Alo) {
  const int tile = blockIdx.x;  // 0..15 (128-row tiles over 2048 rows)
  const int ki = blockIdx.y;    // 0..23
  const int t = threadIdx.x;
#pragma unroll
  for (int half = 0; half < 2; ++half) {
    const int c = t + half * 256;
    const int row = c >> 2, kgs = c & 3;
    const int kg = kgs ^ ((row >> 1) & 3);  // swizzle baked into image
    const float* xr = emb + (size_t)(tile * 128 + row) * HH;
    const int k0 = ki * 32 + kg * 8;
    float4 x0 = *(const float4*)(xr + k0);
    float4 x1 = *(const float4*)(xr + k0 + 4);
    const float xv[8] = {x0.x, x0.y, x0.z, x0.w, x1.x, x1.y, x1.z, x1.w};
    us8 hv, lv;
#pragma unroll
    for (int j = 0; j < 8; ++j) {
      unsigned short h = f2bf_rn(xv[j]);
      hv[j] = h;
      lv[j] = f2bf_rn(xv[j] - bf2f(h));
    }
    const size_t base = (((size_t)tile * 24 + ki) * 512 + c) * 8;
    *(us8*)(Ahi + base) = hv;
    *(us8*)(Alo + base) = lv;
  }
}

// ---------------- prep W1[0:1536] hi/lo images (plain, for pq_mfma B) ----------------
__global__ __launch_bounds__(256) void prep_w1ab_kernel(
    const float* __restrict__ W1, unsigned short* __restrict__ Bhi,
    unsigned short* __restrict__ Blo) {
  const int ki = blockIdx.x;   // 0..23
  const int hby = blockIdx.y;  // 0..11 (cols 0..1535: P cols then Q cols)
  const int t = threadIdx.x;
#pragma unroll
  for (int half = 0; half < 2; ++half) {
    const int c = t + half * 256;
    const int col = c >> 2, kg = c & 3;
    const int gc = hby * 128 + col;
    const float* base = W1 + (gc < 768 ? (size_t)0 : (size_t)HH * HH);
    const int n = (gc < 768) ? gc : gc - 768;
    us8 hv, lv;
#pragma unroll
    for (int j = 0; j < 8; ++j) {
      const int k = ki * 32 + kg * 8 + j;
      float v = base[(size_t)k * HH + n];
      unsigned short h = f2bf_rn(v);
      hv[j] = h;
      lv[j] = f2bf_rn(v - bf2f(h));
    }
    const size_t bo = (((size_t)hby * 24 + ki) * 512 + c) * 8;
    *(us8*)(Bhi + bo) = hv;
    *(us8*)(Blo + bo) = lv;
  }
}

// ---------------- P/Q via split-bf16 MFMA (3-term hi/lo, fp32-class accuracy) ----------------
__global__ __launch_bounds__(256) void pq_mfma_kernel(
    const unsigned short* __restrict__ Ahi, const unsigned short* __restrict__ Alo,
    const unsigned short* __restrict__ Bhi, const unsigned short* __restrict__ Blo,
    float* __restrict__ P, float* __restrict__ Q) {
  __shared__ unsigned short AsmH[128 * 32], AsmL[128 * 32];
  const int tile = blockIdx.x;  // 0..15
  const int hby = blockIdx.y;   // 0..11
  const int tid = threadIdx.x;
  const int lane = tid & 63, w = tid >> 6;
  const int wm = w & 1, wn = w >> 1;
  const int lm = lane & 15, lq = lane >> 4;

  f32x4 acc[4][4];
#pragma unroll
  for (int i = 0; i < 4; ++i)
#pragma unroll
    for (int j = 0; j < 4; ++j) acc[i][j] = (f32x4){0.f, 0.f, 0.f, 0.f};

  const unsigned short* AbH = Ahi + (size_t)tile * 24 * 4096;
  const unsigned short* AbL = Alo + (size_t)tile * 24 * 4096;
  const unsigned short* BbH = Bhi + (size_t)hby * 24 * 4096;
  const unsigned short* BbL = Blo + (size_t)hby * 24 * 4096;
  const int a_off = (wm * 64 + lm) * 32 + (lq ^ ((lm >> 1) & 3)) * 8;
  const int b_off = (wn * 64 + lm) * 32 + lq * 8;

  for (int ki = 0; ki < 24; ++ki) {
    async_copy16(AbH + (size_t)ki * 4096 + tid * 8, AsmH + tid * 8);
    async_copy16(AbH + (size_t)ki * 4096 + (tid + 256) * 8, AsmH + (tid + 256) * 8);
    async_copy16(AbL + (size_t)ki * 4096 + tid * 8, AsmL + tid * 8);
    async_copy16(AbL + (size_t)ki * 4096 + (tid + 256) * 8, AsmL + (tid + 256) * 8);
    bf16x8 bh[4], bl[4];
#pragma unroll
    for (int ni = 0; ni < 4; ++ni) {
      bh[ni] = *reinterpret_cast<const bf16x8*>(BbH + (size_t)ki * 4096 + b_off + ni * 512);
      bl[ni] = *reinterpret_cast<const bf16x8*>(BbL + (size_t)ki * 4096 + b_off + ni * 512);
    }
    __syncthreads();
    bf16x8 ah[4], al[4];
#pragma unroll
    for (int mi = 0; mi < 4; ++mi) {
      ah[mi] = *reinterpret_cast<const bf16x8*>(AsmH + a_off + mi * 512);
      al[mi] = *reinterpret_cast<const bf16x8*>(AsmL + a_off + mi * 512);
    }
#pragma unroll
    for (int ni = 0; ni < 4; ++ni)
#pragma unroll
      for (int mi = 0; mi < 4; ++mi) {
        acc[mi][ni] = __builtin_amdgcn_mfma_f32_16x16x32_bf16(ah[mi], bh[ni], acc[mi][ni], 0, 0, 0);
        acc[mi][ni] = __builtin_amdgcn_mfma_f32_16x16x32_bf16(ah[mi], bl[ni], acc[mi][ni], 0, 0, 0);
        acc[mi][ni] = __builtin_amdgcn_mfma_f32_16x16x32_bf16(al[mi], bh[ni], acc[mi][ni], 0, 0, 0);
      }
    __syncthreads();
  }

  float* Obase = (hby < 6) ? P : Q;
  const int cb = ((hby < 6) ? hby : hby - 6) * 128 + wn * 64 + lm;
  const int rowb = tile * 128 + wm * 64 + lq * 4;
#pragma unroll
  for (int mi = 0; mi < 4; ++mi)
#pragma unroll
    for (int ni = 0; ni < 4; ++ni)
#pragma unroll
      for (int r = 0; r < 4; ++r)
        Obase[(size_t)(rowb + mi * 16 + r) * HH + cb + ni * 16] = acc[mi][ni][r];
}

// ---------------- prep At: bf16(x*y), tiled + bank-swizzled ----------------
__global__ __launch_bounds__(256) void prep_a_kernel(
    const float* __restrict__ emb, const int* __restrict__ spans,
    unsigned short* __restrict__ At, int S, int tileofs) {
  const int tl = blockIdx.x, b = blockIdx.y;
  const int tile = tileofs + tl;
  const int t = threadIdx.x;
#pragma unroll
  for (int half = 0; half < 2; ++half) {
    const int c = t + half * 256;
    const int row = c >> 2, kgs = c & 3;
    const int kg = kgs ^ ((row >> 1) & 3);
    int g = tile * 128 + row;
    if (g >= S) g = S - 1;
    const int s = spans[2 * g], e = spans[2 * g + 1];
    const float* xr = emb + ((size_t)b * NN + s) * HH;
    const float* yr = emb + ((size_t)b * NN + e) * HH;
    unsigned short* dst = At + (((size_t)b * CHT + tl) * 24 * 512 + c) * 8;
    for (int ki = 0; ki < 24; ++ki) {
      const int k0 = ki * 32 + kg * 8;
      float4 x0 = *(const float4*)(xr + k0);
      float4 x1 = *(const float4*)(xr + k0 + 4);
      float4 y0 = *(const float4*)(yr + k0);
      float4 y1 = *(const float4*)(yr + k0 + 4);
      us8 v;
      v[0] = f2bf_rn(x0.x * y0.x); v[1] = f2bf_rn(x0.y * y0.y);
      v[2] = f2bf_rn(x0.z * y0.z); v[3] = f2bf_rn(x0.w * y0.w);
      v[4] = f2bf_rn(x1.x * y1.x); v[5] = f2bf_rn(x1.y * y1.y);
      v[6] = f2bf_rn(x1.z * y1.z); v[7] = f2bf_rn(x1.w * y1.w);
      *(us8*)(dst + (size_t)ki * 4096) = v;
    }
  }
}

// ---------------- MFMA single-bf16 scoring v3 ----------------
__global__ __launch_bounds__(256, 3) void score_mfma3_kernel(
    const int* __restrict__ spans,
    const unsigned short* __restrict__ At, const unsigned short* __restrict__ Bt,
    const float* __restrict__ w_s,
    const float* __restrict__ P, const float* __restrict__ Q, const float* __restrict__ R,
    float* __restrict__ spart, int S, int tileofs) {
  __shared__ unsigned short Asm[128 * 32];
  __shared__ int ssm[128], eem[128], wwm[128];
  __shared__ float sred[128 * 2];

  const int tl = blockIdx.x;
  const int tile = tileofs + tl;
  const int hby = blockIdx.y;
  const int b = blockIdx.z;
  const int tid = threadIdx.x;
  const int lane = tid & 63, w = tid >> 6;
  const int wm = w & 1, wn = w >> 1;
  const int lm = lane & 15, lq = lane >> 4;

  if (tid < 128) {
    int g = tile * 128 + tid;
    int gg = g < S ? g : S - 1;
    int s = spans[2 * gg], e = spans[2 * gg + 1];
    ssm[tid] = s; eem[tid] = e; wwm[tid] = e - s;
  }

  f32x4 acc[4][4];
#pragma unroll
  for (int i = 0; i < 4; ++i)
#pragma unroll
    for (int j = 0; j < 4; ++j) acc[i][j] = (f32x4){0.f, 0.f, 0.f, 0.f};

  const unsigned short* Ab = At + ((size_t)b * CHT + tl) * 24 * 4096;
  const unsigned short* Bb = Bt + (size_t)hby * 24 * 4096;
  const int a_off = (wm * 64 + lm) * 32 + (lq ^ ((lm >> 1) & 3)) * 8;
  const int b_off = (wn * 64 + lm) * 32 + lq * 8;

  for (int ki = 0; ki < 24; ++ki) {
    async_copy16(Ab + (size_t)ki * 4096 + tid * 8, Asm + tid * 8);
    async_copy16(Ab + (size_t)ki * 4096 + (tid + 256) * 8, Asm + (tid + 256) * 8);
    bf16x8 bfr[4];
#pragma unroll
    for (int ni = 0; ni < 4; ++ni)
      bfr[ni] = *reinterpret_cast<const bf16x8*>(Bb + (size_t)ki * 4096 + b_off + ni * 512);
    __syncthreads();
    bf16x8 afr[4];
#pragma unroll
    for (int mi = 0; mi < 4; ++mi)
      afr[mi] = *reinterpret_cast<const bf16x8*>(Asm + a_off + mi * 512);
#pragma unroll
    for (int ni = 0; ni < 4; ++ni)
#pragma unroll
      for (int mi = 0; mi < 4; ++mi)
        acc[mi][ni] = __builtin_amdgcn_mfma_f32_16x16x32_bf16(afr[mi], bfr[ni], acc[mi][ni], 0, 0, 0);
    __syncthreads();
  }

  const int hbg = hby * 128;
  float wsv[4];
#pragma unroll
  for (int ni = 0; ni < 4; ++ni) wsv[ni] = w_s[hbg + wn * 64 + ni * 16 + lm];

#pragma unroll
  for (int mi = 0; mi < 4; ++mi) {
#pragma unroll
    for (int r = 0; r < 4; ++r) {
      const int rowl = wm * 64 + mi * 16 + lq * 4 + r;
      const int s = ssm[rowl], e = eem[rowl], wd = wwm[rowl];
      const float* Pp = P + ((size_t)b * NN + s) * HH + hbg + wn * 64 + lm;
      const float* Qp = Q + ((size_t)b * NN + e) * HH + hbg + wn * 64 + lm;
      const float* Rp = R + (size_t)wd * HH + hbg + wn * 64 + lm;
      float psum = 0.f;
#pragma unroll
      for (int ni = 0; ni < 4; ++ni) {
        float z = acc[mi][ni][r] + Pp[ni * 16] + Qp[ni * 16] + Rp[ni * 16];
        psum = fmaf(gelu_f(z), wsv[ni], psum);
      }
      psum += __shfl_xor(psum, 1);
      psum += __shfl_xor(psum, 2);
      psum += __shfl_xor(psum, 4);
      psum += __shfl_xor(psum, 8);
      if (lm == 0) sred[rowl * 2 + wn] = psum;
    }
  }
  __syncthreads();
  if (tid < 128) {
    int g = tile * 128 + tid;
    if (g < S)
      spart[(size_t)hby * ((size_t)NB * S) + (size_t)b * S + g] = sred[tid * 2] + sred[tid * 2 + 1];
  }
}

// ---------------- combine 6 partials + bias + penalty ----------------
__global__ void combine_kernel(const float* __restrict__ sp, const int* __restrict__ spans,
                               const float* __restrict__ b_s, const int* __restrict__ lengths,
                               float* __restrict__ scores, int S) {
  int idx = blockIdx.x * 256 + threadIdx.x;
  if (idx >= NB * S) return;
  int b = idx / S, i = idx - b * S;
  size_t st = (size_t)NB * S;
  float v = b_s[0];
#pragma unroll
  for (int j = 0; j < 6; ++j) v += sp[j * st + idx];
  if (spans[2 * i + 1] >= lengths[b]) v += -1000000.0f;
  scores[idx] = v;
}

// ---------------- radix pivot + zero band counter ----------------
__global__ __launch_bounds__(1024) void pivot_kernel(const float* __restrict__ scores,
                                                     const int* __restrict__ kptr, int S,
                                                     float* __restrict__ pivotf,
                                                     int* __restrict__ bandcount) {
  const int b = blockIdx.x;
  const int tid = threadIdx.x;
  const float* sc = scores + (size_t)b * S;
  const int k = kptr[0];
  __shared__ unsigned hist[256];
  __shared__ unsigned sh_prefix;
  __shared__ int sh_remaining;
  unsigned prefix = 0;
  int remaining = k;
  for (int round = 0; round < 4; ++round) {
    const int shift = 24 - 8 * round;
    if (tid < 256) hist[tid] = 0;
    __syncthreads();
    for (int i = tid; i < S; i += 1024) {
      unsigned key = f2key(sc[i]);
      if (round == 0 || (key >> (shift + 8)) == prefix)
        atomicAdd(&hist[(key >> shift) & 255u], 1u);
    }
    __syncthreads();
    if (tid == 0) {
      int cum = 0;
      for (int bin = 255; bin >= 0; --bin) {
        int c = (int)hist[bin];
        if (cum + c >= remaining) {
          sh_prefix = (prefix << 8) | (unsigned)bin;
          sh_remaining = remaining - cum;
          break;
        }
        cum += c;
      }
    }
    __syncthreads();
    prefix = sh_prefix;
    remaining = sh_remaining;
    __syncthreads();
  }
  if (tid == 0) {
    pivotf[b] = key2f(prefix);
    bandcount[b] = 0;
  }
}

// ---------------- band collect ----------------
__global__ void band_kernel(const float* __restrict__ scores, const float* __restrict__ pivotf,
                            int* __restrict__ bandcount, int* __restrict__ bandlist, int S) {
  int idx = blockIdx.x * 256 + threadIdx.x;
  if (idx >= NB * S) return;
  int b = idx / S, i = idx - b * S;
  if (fabsf(scores[idx] - pivotf[b]) <= BAND_TAU) {
    int slot = atomicAdd(&bandcount[b], 1);
    if (slot < BANDCAP) bandlist[b * BANDCAP + slot] = i;
  }
}

// ---------------- exact fp32 rescore of band spans ----------------
__global__ __launch_bounds__(256) void rescore_kernel(
    const float* __restrict__ emb, const int* __restrict__ spans,
    const float* __restrict__ W1, const float* __restrict__ w_s,
    const float* __restrict__ b_s, const int* __restrict__ lengths,
    const float* __restrict__ P, const float* __restrict__ Q, const float* __restrict__ R,
    const int* __restrict__ bandcount, const int* __restrict__ bandlist,
    float* __restrict__ scores, int S) {
  const int b = blockIdx.y;
  int cnt = bandcount[b];
  if (cnt > BANDCAP) cnt = BANDCAP;
  if ((int)blockIdx.x >= cnt) return;
  const int i = bandlist[b * BANDCAP + blockIdx.x];
  const int s = spans[2 * i], e = spans[2 * i + 1], wd = e - s;
  const int tid = threadIdx.x;
  __shared__ float prod[HH];
  __shared__ float red[256];
  for (int c = tid; c < HH; c += 256)
    prod[c] = emb[((size_t)b * NN + s) * HH + c] * emb[((size_t)b * NN + e) * HH + c];
  __syncthreads();
  const float* W1c = W1 + (size_t)(2 * HH) * HH;
  float psum = 0.f;
  for (int c0 = 0; c0 < HH; c0 += 256) {
    const int c = c0 + tid;
    float a = P[((size_t)b * NN + s) * HH + c] + Q[((size_t)b * NN + e) * HH + c] + R[(size_t)wd * HH + c];
    for (int k = 0; k < HH; ++k) a = fmaf(prod[k], W1c[(size_t)k * HH + c], a);
    psum = fmaf(gelu_f(a), w_s[c], psum);
  }
  red[tid] = psum;
  __syncthreads();
  for (int off = 128; off > 0; off >>= 1) {
    if (tid < off) red[tid] += red[tid + off];
    __syncthreads();
  }
  if (tid == 0) {
    float v = red[0] + b_s[0];
    if (e >= lengths[b]) v += -1000000.0f;
    scores[(size_t)b * S + i] = v;
  }
}

// ---------------- exact top-k (radix + index-ordered compaction) ----------------
__global__ __launch_bounds__(1024) void topk_kernel(
    const float* __restrict__ scores, const int* __restrict__ spans,
    const int* __restrict__ kptr, int S,
    float* __restrict__ out_spans, int* __restrict__ sel) {
  const int b = blockIdx.x;
  const int tid = threadIdx.x;
  const float* sc = scores + (size_t)b * S;
  const int k = kptr[0];
  __shared__ unsigned hist[256];
  __shared__ unsigned sh_prefix;
  __shared__ int sh_remaining;
  __shared__ int wave_eq[16], wave_sel[16];
  __shared__ int selbase, eqbase;
  unsigned prefix = 0;
  int remaining = k;
  for (int round = 0; round < 4; ++round) {
    const int shift = 24 - 8 * round;
    if (tid < 256) hist[tid] = 0;
    __syncthreads();
    for (int i = tid; i < S; i += 1024) {
      unsigned key = f2key(sc[i]);
      if (round == 0 || (key >> (shift + 8)) == prefix)
        atomicAdd(&hist[(key >> shift) & 255u], 1u);
    }
    __syncthreads();
    if (tid == 0) {
      int cum = 0;
      for (int bin = 255; bin >= 0; --bin) {
        int c = (int)hist[bin];
        if (cum + c >= remaining) {
          sh_prefix = (prefix << 8) | (unsigned)bin;
          sh_remaining = remaining - cum;
          break;
        }
        cum += c;
      }
    }
    __syncthreads();
    prefix = sh_prefix;
    remaining = sh_remaining;
    __syncthreads();
  }
  const unsigned pivot = prefix;
  const int m_eq = remaining;
  if (tid == 0) { selbase = 0; eqbase = 0; }
  __syncthreads();
  const int lane = tid & 63, wv = tid >> 6;
  for (int base = 0; base < S; base += 1024) {
    const int i = base + tid;
    const bool inb = (i < S);
    const unsigned key = inb ? f2key(sc[i]) : 0u;
    const bool gt = inb && (key > pivot);
    const bool eq = inb && (key == pivot);
    unsigned long long mm = __ballot(eq);
    int eqpre = __popcll(mm & ((1ull << lane) - 1ull));
    if (lane == 0) wave_eq[wv] = __popcll(mm);
    __syncthreads();
    int eqpref = 0, eqtot = 0;
#pragma unroll
    for (int w2 = 0; w2 < 16; ++w2) {
      int c = wave_eq[w2];
      if (w2 < wv) eqpref += c;
      eqtot += c;
    }
    const bool take_eq = eq && (eqbase + eqpref + eqpre < m_eq);
    const bool sf = gt || take_eq;
    unsigned long long sm = __ballot(sf);
    int spre = __popcll(sm & ((1ull << lane) - 1ull));
    if (lane == 0) wave_sel[wv] = __popcll(sm);
    __syncthreads();
    int spref = 0, stot = 0;
#pragma unroll
    for (int w2 = 0; w2 < 16; ++w2) {
      int c = wave_sel[w2];
      if (w2 < wv) spref += c;
      stot += c;
    }
    if (sf) {
      const int j = selbase + spref + spre;
      out_spans[(b * KTOP + j) * 2 + 0] = (float)spans[2 * i];
      out_spans[(b * KTOP + j) * 2 + 1] = (float)spans[2 * i + 1];
      sel[b * KTOP + j] = i;
    }
    __syncthreads();
    if (tid == 0) { selbase += stot; eqbase += eqtot; }
    __syncthreads();
  }
}

// ---------------- gather part: fp32 (x*y)@W1c partial over K-chunk of 128 ----------------
__global__ __launch_bounds__(256) void gather_part_kernel(
    const float* __restrict__ emb, const int* __restrict__ spans,
    const float* __restrict__ W1, const int* __restrict__ sel,
    float* __restrict__ Gpart) {
  __shared__ float As[KT][ASTR];
  __shared__ float Bs[KT][BSTR];
  __shared__ int ssm[MT], eem[MT];
  const int tile = blockIdx.x;
  const int hby6 = blockIdx.y;
  const int hb = (hby6 / 6) * NT;
  const int ks = hby6 % 6;
  const int b = blockIdx.z;
  const int tid = threadIdx.x;
  const int th = tid & 31, tw = tid >> 5;
  if (tid < MT) {
    int j = tile * MT + tid;
    if (j >= KTOP) j = KTOP - 1;
    int i = sel[b * KTOP + j];
    ssm[tid] = spans[2 * i];
    eem[tid] = spans[2 * i + 1];
  }
  __syncthreads();
  const int m0 = tid >> 3, m1 = m0 + 32;
  const int d0 = (tid & 7) << 2;
  const size_t ebase = (size_t)b * NN * HH;
  const size_t rx0 = ebase + (size_t)ssm[m0] * HH;
  const size_t ry0 = ebase + (size_t)eem[m0] * HH;
  const size_t rx1 = ebase + (size_t)ssm[m1] * HH;
  const size_t ry1 = ebase + (size_t)eem[m1] * HH;
  const float* W1c = W1 + (size_t)(2 * HH) * HH;
  const int bc = (tid & 63) << 2;
  const int br = tid >> 6;
  float acc[8][8];
#pragma unroll
  for (int i = 0; i < 8; ++i)
#pragma unroll
    for (int j = 0; j < 8; ++j) acc[i][j] = 0.f;
  const int k0 = ks * 128;
  for (int it = 0; it < 4; ++it) {
    const int kt = k0 + it * KT;
    float4 x0 = *reinterpret_cast<const float4*>(emb + rx0 + kt + d0);
    float4 y0 = *reinterpret_cast<const float4*>(emb + ry0 + kt + d0);
    float4 x1 = *reinterpret_cast<const float4*>(emb + rx1 + kt + d0);
    float4 y1 = *reinterpret_cast<const float4*>(emb + ry1 + kt + d0);
    float4 bw[8];
#pragma unroll
    for (int r = 0; r < 8; ++r)
      bw[r] = *reinterpret_cast<const float4*>(W1c + (size_t)(kt + br + 4 * r) * HH + hb + bc);
    __syncthreads();
    As[d0 + 0][m0] = x0.x * y0.x; As[d0 + 1][m0] = x0.y * y0.y;
    As[d0 + 2][m0] = x0.z * y0.z; As[d0 + 3][m0] = x0.w * y0.w;
    As[d0 + 0][m1] = x1.x * y1.x; As[d0 + 1][m1] = x1.y * y1.y;
    As[d0 + 2][m1] = x1.z * y1.z; As[d0 + 3][m1] = x1.w * y1.w;
#pragma unroll
    for (int r = 0; r < 8; ++r)
      *reinterpret_cast<float4*>(&Bs[br + 4 * r][bc]) = bw[r];
    __syncthreads();
#pragma unroll
    for (int d = 0; d < KT; ++d) {
      const float4 a0 = *reinterpret_cast<const float4*>(&As[d][tw * 4]);
      const float4 a1 = *reinterpret_cast<const float4*>(&As[d][tw * 4 + 32]);
      const float4 b0 = *reinterpret_cast<const float4*>(&Bs[d][th * 4]);
      const float4 b1v = *reinterpret_cast<const float4*>(&Bs[d][th * 4 + 128]);
      const float av[8] = {a0.x, a0.y, a0.z, a0.w, a1.x, a1.y, a1.z, a1.w};
      const float bv[8] = {b0.x, b0.y, b0.z, b0.w, b1v.x, b1v.y, b1v.z, b1v.w};
#pragma unroll
      for (int mi = 0; mi < 8; ++mi)
#pragma unroll
        for (int ni = 0; ni < 8; ++ni)
          acc[mi][ni] = fmaf(av[mi], bv[ni], acc[mi][ni]);
    }
  }
#pragma unroll
  for (int mi = 0; mi < 8; ++mi) {
    const int m = tw * 4 + (mi & 3) + ((mi >> 2) << 5);
    float* op = Gpart + (((size_t)ks * NB + b) * GPAD + tile * MT + m) * HH + hb;
    *reinterpret_cast<float4*>(op + th * 4) = make_float4(acc[mi][0], acc[mi][1], acc[mi][2], acc[mi][3]);
    *reinterpret_cast<float4*>(op + th * 4 + 128) = make_float4(acc[mi][4], acc[mi][5], acc[mi][6], acc[mi][7]);
  }
}

// ---------------- gather fin: sum partials + PQR -> gelu -> h + score partials ----------------
__global__ __launch_bounds__(256) void gather_fin_kernel(
    const float* __restrict__ Gpart, const int* __restrict__ spans,
    const int* __restrict__ sel,
    const float* __restrict__ P, const float* __restrict__ Q, const float* __restrict__ R,
    const float* __restrict__ w_s, float* __restrict__ outh, float* __restrict__ spartg) {
  __shared__ int ssm[16], eem[16], wwm[16], vvm[16];
  __shared__ float sred[16];
  const int t16 = blockIdx.x;
  const int hby = blockIdx.y;
  const int b = blockIdx.z;
  const int tid = threadIdx.x;
  if (tid < 16) {
    int j = t16 * 16 + tid;
    int valid = (j < KTOP) ? 1 : 0;
    int jj = valid ? j : KTOP - 1;
    int i = sel[b * KTOP + jj];
    ssm[tid] = spans[2 * i];
    eem[tid] = spans[2 * i + 1];
    wwm[tid] = eem[tid] - ssm[tid];
    vvm[tid] = valid;
  }
  __syncthreads();
  const int row = tid >> 4;
  const int cc = tid & 15;
  const int g448 = t16 * 16 + row;
  const int co = hby * 128 + cc * 8;
  float v[8];
#pragma unroll
  for (int i = 0; i < 8; ++i) v[i] = 0.f;
#pragma unroll
  for (int ks = 0; ks < 6; ++ks) {
    const float* gp = Gpart + (((size_t)ks * NB + b) * GPAD + g448) * HH + co;
    float4 a = *(const float4*)gp;
    float4 c = *(const float4*)(gp + 4);
    v[0] += a.x; v[1] += a.y; v[2] += a.z; v[3] += a.w;
    v[4] += c.x; v[5] += c.y; v[6] += c.z; v[7] += c.w;
  }
  const int s = ssm[row], e = eem[row], wd = wwm[row];
  const float* Pp = P + ((size_t)b * NN + s) * HH + co;
  const float* Qp = Q + ((size_t)b * NN + e) * HH + co;
  const float* Rp = R + (size_t)wd * HH + co;
  float4 p0 = *(const float4*)Pp, p1 = *(const float4*)(Pp + 4);
  float4 q0 = *(const float4*)Qp, q1 = *(const float4*)(Qp + 4);
  float4 r0 = *(const float4*)Rp, r1 = *(const float4*)(Rp + 4);
  v[0] += p0.x + q0.x + r0.x; v[1] += p0.y + q0.y + r0.y;
  v[2] += p0.z + q0.z + r0.z; v[3] += p0.w + q0.w + r0.w;
  v[4] += p1.x + q1.x + r1.x; v[5] += p1.y + q1.y + r1.y;
  v[6] += p1.z + q1.z + r1.z; v[7] += p1.w + q1.w + r1.w;
  float gl[8];
#pragma unroll
  for (int i = 0; i < 8; ++i) gl[i] = gelu_f(v[i]);
  float psum = 0.f;
  if (vvm[row]) {
    const int j = t16 * 16 + row;
    float* op = outh + (size_t)(b * KTOP + j) * HH + co;
    *(float4*)op = make_float4(gl[0], gl[1], gl[2], gl[3]);
    *(float4*)(op + 4) = make_float4(gl[4], gl[5], gl[6], gl[7]);
    const float4 w0 = *(const float4*)(w_s + co);
    const float4 w1 = *(const float4*)(w_s + co + 4);
    psum = gl[0] * w0.x + gl[1] * w0.y + gl[2] * w0.z + gl[3] * w0.w +
           gl[4] * w1.x + gl[5] * w1.y + gl[6] * w1.z + gl[7] * w1.w;
  }
  psum += __shfl_xor(psum, 1);
  psum += __shfl_xor(psum, 2);
  psum += __shfl_xor(psum, 4);
  psum += __shfl_xor(psum, 8);
  const int lane = tid & 63, wv = tid >> 6;
  if ((lane & 15) == 0) sred[wv * 4 + (lane >> 4)] = psum;
  __syncthreads();
  if (tid < 16)
    spartg[(size_t)hby * (NB * SP416) + b * SP416 + t16 * 16 + tid] = sred[tid];
}

// ---------------- final scores for selected spans ----------------
__global__ void score_fin_kernel(const float* __restrict__ spartg, const int* __restrict__ sel,
                                 const int* __restrict__ spans, const float* __restrict__ b_s,
                                 const int* __restrict__ lengths, float* __restrict__ out_scores) {
  int idx = blockIdx.x * 256 + threadIdx.x;
  if (idx >= NB * KTOP) return;
  int b = idx / KTOP, j = idx - b * KTOP;
  float v = b_s[0];
#pragma unroll
  for (int hby = 0; hby < 6; ++hby)
    v += spartg[(size_t)hby * (NB * SP416) + b * SP416 + j];
  int i = sel[idx];
  if (spans[2 * i + 1] >= lengths[b]) v += -1000000.0f;
  out_scores[idx] = v;
}

extern "C" void kernel_launch(void* const* d_in, const int* in_sizes, int n_in,
                              void* d_out, int out_size, void* d_ws, size_t ws_size,
                              hipStream_t stream) {
  const float* emb = (const float*)d_in[0];
  const int* mask = (const int*)d_in[1];
  const int* spans = (const int*)d_in[2];
  const float* wemb = (const float*)d_in[3];
  const float* W1 = (const float*)d_in[4];
  const float* b1 = (const float*)d_in[5];
  const float* w_s = (const float*)d_in[6];
  const float* b_s = (const float*)d_in[7];
  const int* kptr = (const int*)d_in[8];
  const int S = in_sizes[2] / 2;  // 30285
  float* out = (float*)d_out;

  char* wp = (char*)d_ws;
  auto take = [&](size_t bytes) {
    char* p = wp;
    wp += (bytes + 63) & ~(size_t)63;
    return p;
  };
  float* Pb = (float*)take((size_t)NB * NN * HH * 4);
  float* Qb = (float*)take((size_t)NB * NN * HH * 4);
  float* Rb = (float*)take((size_t)MAXW * HH * 4);
  float* spart = (float*)take(6 * (size_t)NB * S * 4);
  float* scoresb = (float*)take((size_t)NB * S * 4);
  float* spartg = (float*)take(6 * (size_t)NB * SP416 * 4);
  float* Gpart = (float*)take(6 * (size_t)NB * GPAD * HH * 4);  // 16.5 MB
  float* pivotf = (float*)take(NB * 4);
  unsigned short* At = (unsigned short*)take((size_t)NB * CHT * 24 * 4096 * 2);  // 47 MB
  unsigned short* Bt = (unsigned short*)take((size_t)6 * 24 * 4096 * 2);
  int* selb = (int*)take(NB * KTOP * 4);
  int* lengthsb = (int*)take(NB * 4);
  int* bandcount = (int*)take(NB * 4);
  int* bandlist = (int*)take((size_t)NB * BANDCAP * 4);

  // pq_mfma hi/lo images alias the At buffer (pq phase completes before prep_a
  // first writes At — stream-ordered). Sizes: A 16*24*4096 shorts (3 MB) x2,
  // B 12*24*4096 shorts (2.25 MB) x2 -> 10.5 MB << 47 MB.
  unsigned short* AimgHi = At;
  unsigned short* AimgLo = AimgHi + (size_t)16 * 24 * 4096;
  unsigned short* BimgHi = AimgLo + (size_t)16 * 24 * 4096;
  unsigned short* BimgLo = BimgHi + (size_t)12 * 24 * 4096;

  const size_t OFF1 = (size_t)NB * KTOP * HH;    // embs
  const size_t OFF2 = OFF1 + (size_t)NB * KTOP;  // scores | spans

  const int tiles = (S + 127) / 128;  // 237

  len_kernel<<<dim3(1), dim3(256), 0, stream>>>(mask, lengthsb);
  r_kernel<<<dim3(MAXW), dim3(256), 0, stream>>>(wemb, W1, b1, Rb);
  prep_bt_kernel<<<dim3(24, 6), dim3(256), 0, stream>>>(W1, Bt);
  prep_emb_hl_kernel<<<dim3(16, 24), dim3(256), 0, stream>>>(emb, AimgHi, AimgLo);
  prep_w1ab_kernel<<<dim3(24, 12), dim3(256), 0, stream>>>(W1, BimgHi, BimgLo);
  pq_mfma_kernel<<<dim3(16, 12), dim3(256), 0, stream>>>(AimgHi, AimgLo, BimgHi, BimgLo, Pb, Qb);

  for (int pass = 0; pass < 2; ++pass) {
    const int ofs = pass * CHT;
    const int nt = (pass == 0) ? CHT : (tiles - CHT);
    prep_a_kernel<<<dim3(nt, NB), dim3(256), 0, stream>>>(emb, spans, At, S, ofs);
    score_mfma3_kernel<<<dim3(nt, 6, NB), dim3(256), 0, stream>>>(
        spans, At, Bt, w_s, Pb, Qb, Rb, spart, S, ofs);
  }

  combine_kernel<<<dim3((NB * S + 255) / 256), dim3(256), 0, stream>>>(
      spart, spans, b_s, lengthsb, scoresb, S);
  pivot_kernel<<<dim3(NB), dim3(1024), 0, stream>>>(scoresb, kptr, S, pivotf, bandcount);
  band_kernel<<<dim3((NB * S + 255) / 256), dim3(256), 0, stream>>>(
      scoresb, pivotf, bandcount, bandlist, S);
  rescore_kernel<<<dim3(BANDCAP, NB), dim3(256), 0, stream>>>(
      emb, spans, W1, w_s, b_s, lengthsb, Pb, Qb, Rb, bandcount, bandlist, scoresb, S);
  topk_kernel<<<dim3(NB), dim3(1024), 0, stream>>>(scoresb, spans, kptr, S, out + OFF2, selb);
  gather_part_kernel<<<dim3(7, 18, NB), dim3(256), 0, stream>>>(emb, spans, W1, selb, Gpart);
  gather_fin_kernel<<<dim3(26, 6, NB), dim3(256), 0, stream>>>(
      Gpart, spans, selb, Pb, Qb, Rb, w_s, out, spartg);
  score_fin_kernel<<<dim3((NB * KTOP + 255) / 256), dim3(256), 0, stream>>>(
      spartg, selb, spans, b_s, lengthsb, out + OFF1);
}

// Round 7
// 560.308 us; speedup vs baseline: 1.6079x; 1.1354x over previous
//
#include <hip/hip_runtime.h>
#include <math.h>

#define NB 2
#define NN 1024
#define HH 768
#define MAXW 30
#define KTOP 409
#define BANDCAP 4096
#define BAND_TAU 2e-2f
#define FILTCAP 6144
#define CHT 120    // tile-chunk stride for At buffer (two passes: 120 + 117)
#define GPAD 448   // 7*64 padded selected-span rows
#define SP416 416  // 26*16 padded rows for spartg slabs

typedef __attribute__((ext_vector_type(4))) float f32x4;
typedef __attribute__((ext_vector_type(8))) __bf16 bf16x8;
typedef __attribute__((ext_vector_type(8))) unsigned short us8;

constexpr int MT = 64, NT = 256, KT = 32;
constexpr int ASTR = MT + 4;
constexpr int BSTR = NT + 4;

__device__ __forceinline__ float gelu_f(float z) {
  return 0.5f * z * (1.0f + erff(z * 0.70710678118654752440f));
}
__device__ __forceinline__ unsigned f2key(float f) {
  unsigned u = __float_as_uint(f);
  return (u & 0x80000000u) ? ~u : (u | 0x80000000u);
}
__device__ __forceinline__ float key2f(unsigned k) {
  unsigned u = (k & 0x80000000u) ? (k & 0x7fffffffu) : ~k;
  return __uint_as_float(u);
}
__device__ __forceinline__ unsigned short f2bf_rn(float f) {
  unsigned u = __float_as_uint(f);
  unsigned r = u + 0x7fffu + ((u >> 16) & 1u);
  return (unsigned short)(r >> 16);
}
__device__ __forceinline__ float bf2f(unsigned short h) {
  return __uint_as_float(((unsigned)h) << 16);
}
__device__ __forceinline__ void async_copy16(const void* g, void* l) {
  __builtin_amdgcn_global_load_lds(
      (const __attribute__((address_space(1))) unsigned int*)g,
      (__attribute__((address_space(3))) unsigned int*)l, 16, 0, 0);
}

// ---------------- lengths ----------------
__global__ void len_kernel(const int* __restrict__ mask, int* __restrict__ lengths) {
  __shared__ int red[256];
  for (int b = 0; b < NB; ++b) {
    int s = 0;
    for (int i = threadIdx.x; i < NN; i += 256) s += mask[b * NN + i];
    red[threadIdx.x] = s;
    __syncthreads();
    for (int off = 128; off > 0; off >>= 1) {
      if (threadIdx.x < off) red[threadIdx.x] += red[threadIdx.x + off];
      __syncthreads();
    }
    if (threadIdx.x == 0) lengths[b] = red[0];
    __syncthreads();
  }
}

// ---------------- R[w,h] ----------------
__global__ void r_kernel(const float* __restrict__ wemb, const float* __restrict__ W1,
                         const float* __restrict__ b1, float* __restrict__ R) {
  int w = blockIdx.x;
  for (int h = threadIdx.x; h < HH; h += 256) {
    float acc = b1[h];
    for (int j = 0; j < 20; ++j)
      acc = fmaf(wemb[w * 20 + j], W1[(size_t)(3 * HH + j) * HH + h], acc);
    R[w * HH + h] = acc;
  }
}

// ---------------- prep Bt (W1c single-bf16, for approx scoring) ----------------
__global__ __launch_bounds__(256) void prep_bt_kernel(const float* __restrict__ W1,
                                                      unsigned short* __restrict__ Bt) {
  const int ki = blockIdx.x;
  const int hby = blockIdx.y;
  const float* W1c = W1 + (size_t)(2 * HH) * HH;
  const int t = threadIdx.x;
#pragma unroll
  for (int half = 0; half < 2; ++half) {
    const int c = t + half * 256;
    const int col = c >> 2, kg = c & 3;
    us8 v;
#pragma unroll
    for (int j = 0; j < 8; ++j) {
      const int k = ki * 32 + kg * 8 + j;
      v[j] = f2bf_rn(W1c[(size_t)k * HH + hby * 128 + col]);
    }
    *(us8*)(Bt + ((size_t)(hby * 24 + ki) * 512 + c) * 8) = v;
  }
}

// ---------------- prep emb hi/lo images (swizzled, for pq_mfma A) ----------------
__global__ __launch_bounds__(256) void prep_emb_hl_kernel(
    const float* __restrict__ emb, unsigned short* __restrict__ Ahi,
    unsigned short* __restrict__ Alo) {
  const int tile = blockIdx.x;
  const int ki = blockIdx.y;
  const int t = threadIdx.x;
#pragma unroll
  for (int half = 0; half < 2; ++half) {
    const int c = t + half * 256;
    const int row = c >> 2, kgs = c & 3;
    const int kg = kgs ^ ((row >> 1) & 3);
    const float* xr = emb + (size_t)(tile * 128 + row) * HH;
    const int k0 = ki * 32 + kg * 8;
    float4 x0 = *(const float4*)(xr + k0);
    float4 x1 = *(const float4*)(xr + k0 + 4);
    const float xv[8] = {x0.x, x0.y, x0.z, x0.w, x1.x, x1.y, x1.z, x1.w};
    us8 hv, lv;
#pragma unroll
    for (int j = 0; j < 8; ++j) {
      unsigned short h = f2bf_rn(xv[j]);
      hv[j] = h;
      lv[j] = f2bf_rn(xv[j] - bf2f(h));
    }
    const size_t base = (((size_t)tile * 24 + ki) * 512 + c) * 8;
    *(us8*)(Ahi + base) = hv;
    *(us8*)(Alo + base) = lv;
  }
}

// ---------------- prep W1[0:1536] hi/lo images (plain, for pq_mfma B) ----------------
__global__ __launch_bounds__(256) void prep_w1ab_kernel(
    const float* __restrict__ W1, unsigned short* __restrict__ Bhi,
    unsigned short* __restrict__ Blo) {
  const int ki = blockIdx.x;
  const int hby = blockIdx.y;
  const int t = threadIdx.x;
#pragma unroll
  for (int half = 0; half < 2; ++half) {
    const int c = t + half * 256;
    const int col = c >> 2, kg = c & 3;
    const int gc = hby * 128 + col;
    const float* base = W1 + (gc < 768 ? (size_t)0 : (size_t)HH * HH);
    const int n = (gc < 768) ? gc : gc - 768;
    us8 hv, lv;
#pragma unroll
    for (int j = 0; j < 8; ++j) {
      const int k = ki * 32 + kg * 8 + j;
      float v = base[(size_t)k * HH + n];
      unsigned short h = f2bf_rn(v);
      hv[j] = h;
      lv[j] = f2bf_rn(v - bf2f(h));
    }
    const size_t bo = (((size_t)hby * 24 + ki) * 512 + c) * 8;
    *(us8*)(Bhi + bo) = hv;
    *(us8*)(Blo + bo) = lv;
  }
}

// ---------------- P/Q via split-bf16 MFMA ----------------
__global__ __launch_bounds__(256) void pq_mfma_kernel(
    const unsigned short* __restrict__ Ahi, const unsigned short* __restrict__ Alo,
    const unsigned short* __restrict__ Bhi, const unsigned short* __restrict__ Blo,
    float* __restrict__ P, float* __restrict__ Q) {
  __shared__ unsigned short AsmH[128 * 32], AsmL[128 * 32];
  const int tile = blockIdx.x;
  const int hby = blockIdx.y;
  const int tid = threadIdx.x;
  const int lane = tid & 63, w = tid >> 6;
  const int wm = w & 1, wn = w >> 1;
  const int lm = lane & 15, lq = lane >> 4;

  f32x4 acc[4][4];
#pragma unroll
  for (int i = 0; i < 4; ++i)
#pragma unroll
    for (int j = 0; j < 4; ++j) acc[i][j] = (f32x4){0.f, 0.f, 0.f, 0.f};

  const unsigned short* AbH = Ahi + (size_t)tile * 24 * 4096;
  const unsigned short* AbL = Alo + (size_t)tile * 24 * 4096;
  const unsigned short* BbH = Bhi + (size_t)hby * 24 * 4096;
  const unsigned short* BbL = Blo + (size_t)hby * 24 * 4096;
  const int a_off = (wm * 64 + lm) * 32 + (lq ^ ((lm >> 1) & 3)) * 8;
  const int b_off = (wn * 64 + lm) * 32 + lq * 8;

  for (int ki = 0; ki < 24; ++ki) {
    async_copy16(AbH + (size_t)ki * 4096 + tid * 8, AsmH + tid * 8);
    async_copy16(AbH + (size_t)ki * 4096 + (tid + 256) * 8, AsmH + (tid + 256) * 8);
    async_copy16(AbL + (size_t)ki * 4096 + tid * 8, AsmL + tid * 8);
    async_copy16(AbL + (size_t)ki * 4096 + (tid + 256) * 8, AsmL + (tid + 256) * 8);
    bf16x8 bh[4], bl[4];
#pragma unroll
    for (int ni = 0; ni < 4; ++ni) {
      bh[ni] = *reinterpret_cast<const bf16x8*>(BbH + (size_t)ki * 4096 + b_off + ni * 512);
      bl[ni] = *reinterpret_cast<const bf16x8*>(BbL + (size_t)ki * 4096 + b_off + ni * 512);
    }
    __syncthreads();
    bf16x8 ah[4], al[4];
#pragma unroll
    for (int mi = 0; mi < 4; ++mi) {
      ah[mi] = *reinterpret_cast<const bf16x8*>(AsmH + a_off + mi * 512);
      al[mi] = *reinterpret_cast<const bf16x8*>(AsmL + a_off + mi * 512);
    }
#pragma unroll
    for (int ni = 0; ni < 4; ++ni)
#pragma unroll
      for (int mi = 0; mi < 4; ++mi) {
        acc[mi][ni] = __builtin_amdgcn_mfma_f32_16x16x32_bf16(ah[mi], bh[ni], acc[mi][ni], 0, 0, 0);
        acc[mi][ni] = __builtin_amdgcn_mfma_f32_16x16x32_bf16(ah[mi], bl[ni], acc[mi][ni], 0, 0, 0);
        acc[mi][ni] = __builtin_amdgcn_mfma_f32_16x16x32_bf16(al[mi], bh[ni], acc[mi][ni], 0, 0, 0);
      }
    __syncthreads();
  }

  float* Obase = (hby < 6) ? P : Q;
  const int cb = ((hby < 6) ? hby : hby - 6) * 128 + wn * 64 + lm;
  const int rowb = tile * 128 + wm * 64 + lq * 4;
#pragma unroll
  for (int mi = 0; mi < 4; ++mi)
#pragma unroll
    for (int ni = 0; ni < 4; ++ni)
#pragma unroll
      for (int r = 0; r < 4; ++r)
        Obase[(size_t)(rowb + mi * 16 + r) * HH + cb + ni * 16] = acc[mi][ni][r];
}

// ---------------- prep At: bf16(x*y), tiled + bank-swizzled ----------------
__global__ __launch_bounds__(256) void prep_a_kernel(
    const float* __restrict__ emb, const int* __restrict__ spans,
    unsigned short* __restrict__ At, int S, int tileofs) {
  const int tl = blockIdx.x, b = blockIdx.y;
  const int tile = tileofs + tl;
  const int t = threadIdx.x;
#pragma unroll
  for (int half = 0; half < 2; ++half) {
    const int c = t + half * 256;
    const int row = c >> 2, kgs = c & 3;
    const int kg = kgs ^ ((row >> 1) & 3);
    int g = tile * 128 + row;
    if (g >= S) g = S - 1;
    const int s = spans[2 * g], e = spans[2 * g + 1];
    const float* xr = emb + ((size_t)b * NN + s) * HH;
    const float* yr = emb + ((size_t)b * NN + e) * HH;
    unsigned short* dst = At + (((size_t)b * CHT + tl) * 24 * 512 + c) * 8;
    for (int ki = 0; ki < 24; ++ki) {
      const int k0 = ki * 32 + kg * 8;
      float4 x0 = *(const float4*)(xr + k0);
      float4 x1 = *(const float4*)(xr + k0 + 4);
      float4 y0 = *(const float4*)(yr + k0);
      float4 y1 = *(const float4*)(yr + k0 + 4);
      us8 v;
      v[0] = f2bf_rn(x0.x * y0.x); v[1] = f2bf_rn(x0.y * y0.y);
      v[2] = f2bf_rn(x0.z * y0.z); v[3] = f2bf_rn(x0.w * y0.w);
      v[4] = f2bf_rn(x1.x * y1.x); v[5] = f2bf_rn(x1.y * y1.y);
      v[6] = f2bf_rn(x1.z * y1.z); v[7] = f2bf_rn(x1.w * y1.w);
      *(us8*)(dst + (size_t)ki * 4096) = v;
    }
  }
}

// ---------------- MFMA single-bf16 scoring v3 ----------------
__global__ __launch_bounds__(256, 3) void score_mfma3_kernel(
    const int* __restrict__ spans,
    const unsigned short* __restrict__ At, const unsigned short* __restrict__ Bt,
    const float* __restrict__ w_s,
    const float* __restrict__ P, const float* __restrict__ Q, const float* __restrict__ R,
    float* __restrict__ spart, int S, int tileofs) {
  __shared__ unsigned short Asm[128 * 32];
  __shared__ int ssm[128], eem[128], wwm[128];
  __shared__ float sred[128 * 2];

  const int tl = blockIdx.x;
  const int tile = tileofs + tl;
  const int hby = blockIdx.y;
  const int b = blockIdx.z;
  const int tid = threadIdx.x;
  const int lane = tid & 63, w = tid >> 6;
  const int wm = w & 1, wn = w >> 1;
  const int lm = lane & 15, lq = lane >> 4;

  if (tid < 128) {
    int g = tile * 128 + tid;
    int gg = g < S ? g : S - 1;
    int s = spans[2 * gg], e = spans[2 * gg + 1];
    ssm[tid] = s; eem[tid] = e; wwm[tid] = e - s;
  }

  f32x4 acc[4][4];
#pragma unroll
  for (int i = 0; i < 4; ++i)
#pragma unroll
    for (int j = 0; j < 4; ++j) acc[i][j] = (f32x4){0.f, 0.f, 0.f, 0.f};

  const unsigned short* Ab = At + ((size_t)b * CHT + tl) * 24 * 4096;
  const unsigned short* Bb = Bt + (size_t)hby * 24 * 4096;
  const int a_off = (wm * 64 + lm) * 32 + (lq ^ ((lm >> 1) & 3)) * 8;
  const int b_off = (wn * 64 + lm) * 32 + lq * 8;

  for (int ki = 0; ki < 24; ++ki) {
    async_copy16(Ab + (size_t)ki * 4096 + tid * 8, Asm + tid * 8);
    async_copy16(Ab + (size_t)ki * 4096 + (tid + 256) * 8, Asm + (tid + 256) * 8);
    bf16x8 bfr[4];
#pragma unroll
    for (int ni = 0; ni < 4; ++ni)
      bfr[ni] = *reinterpret_cast<const bf16x8*>(Bb + (size_t)ki * 4096 + b_off + ni * 512);
    __syncthreads();
    bf16x8 afr[4];
#pragma unroll
    for (int mi = 0; mi < 4; ++mi)
      afr[mi] = *reinterpret_cast<const bf16x8*>(Asm + a_off + mi * 512);
#pragma unroll
    for (int ni = 0; ni < 4; ++ni)
#pragma unroll
      for (int mi = 0; mi < 4; ++mi)
        acc[mi][ni] = __builtin_amdgcn_mfma_f32_16x16x32_bf16(afr[mi], bfr[ni], acc[mi][ni], 0, 0, 0);
    __syncthreads();
  }

  const int hbg = hby * 128;
  float wsv[4];
#pragma unroll
  for (int ni = 0; ni < 4; ++ni) wsv[ni] = w_s[hbg + wn * 64 + ni * 16 + lm];

#pragma unroll
  for (int mi = 0; mi < 4; ++mi) {
#pragma unroll
    for (int r = 0; r < 4; ++r) {
      const int rowl = wm * 64 + mi * 16 + lq * 4 + r;
      const int s = ssm[rowl], e = eem[rowl], wd = wwm[rowl];
      const float* Pp = P + ((size_t)b * NN + s) * HH + hbg + wn * 64 + lm;
      const float* Qp = Q + ((size_t)b * NN + e) * HH + hbg + wn * 64 + lm;
      const float* Rp = R + (size_t)wd * HH + hbg + wn * 64 + lm;
      float psum = 0.f;
#pragma unroll
      for (int ni = 0; ni < 4; ++ni) {
        float z = acc[mi][ni][r] + Pp[ni * 16] + Qp[ni * 16] + Rp[ni * 16];
        psum = fmaf(gelu_f(z), wsv[ni], psum);
      }
      psum += __shfl_xor(psum, 1);
      psum += __shfl_xor(psum, 2);
      psum += __shfl_xor(psum, 4);
      psum += __shfl_xor(psum, 8);
      if (lm == 0) sred[rowl * 2 + wn] = psum;
    }
  }
  __syncthreads();
  if (tid < 128) {
    int g = tile * 128 + tid;
    if (g < S)
      spart[(size_t)hby * ((size_t)NB * S) + (size_t)b * S + g] = sred[tid * 2] + sred[tid * 2 + 1];
  }
}

// ---------------- combine 6 partials + bias + penalty ----------------
__global__ void combine_kernel(const float* __restrict__ sp, const int* __restrict__ spans,
                               const float* __restrict__ b_s, const int* __restrict__ lengths,
                               float* __restrict__ scores, int S) {
  int idx = blockIdx.x * 256 + threadIdx.x;
  if (idx >= NB * S) return;
  int b = idx / S, i = idx - b * S;
  size_t st = (size_t)NB * S;
  float v = b_s[0];
#pragma unroll
  for (int j = 0; j < 6; ++j) v += sp[j * st + idx];
  if (spans[2 * i + 1] >= lengths[b]) v += -1000000.0f;
  scores[idx] = v;
}

// ---------------- zero hist/counters ----------------
__global__ void zero_kernel(unsigned* __restrict__ hist, int* __restrict__ bandcount,
                            int* __restrict__ filtcount) {
  int i = blockIdx.x * 256 + threadIdx.x;  // 512*256 = 131072 = NB*65536
  hist[i] = 0;
  if (blockIdx.x == 0 && threadIdx.x < NB) {
    bandcount[threadIdx.x] = 0;
    filtcount[threadIdx.x] = 0;
  }
}

// ---------------- parallel 16-bit key histogram ----------------
__global__ void hist16_kernel(const float* __restrict__ scores, unsigned* __restrict__ hist,
                              int S) {
  int idx = blockIdx.x * 256 + threadIdx.x;
  if (idx >= NB * S) return;
  int b = idx / S;
  unsigned key = f2key(scores[idx]) >> 16;
  atomicAdd(&hist[(size_t)b * 65536 + key], 1u);
}

// ---------------- scan 65536 bins descending -> kth bin lower edge (pivot est.) ----------------
__global__ __launch_bounds__(1024) void scan16_kernel(const unsigned* __restrict__ hist,
                                                      const int* __restrict__ kptr,
                                                      float* __restrict__ pivotf) {
  const int b = blockIdx.x;
  const unsigned* hb = hist + (size_t)b * 65536;
  const int tid = threadIdx.x;
  const unsigned k = (unsigned)kptr[0];
  __shared__ unsigned acc[1024];
  unsigned s = 0;
  for (int j = 0; j < 64; ++j) s += hb[tid * 64 + j];
  const unsigned mysum = s;
  acc[tid] = s;
  __syncthreads();
  // inclusive suffix sum: acc[t] = sum_{t'>=t} psum[t']
  for (int off = 1; off < 1024; off <<= 1) {
    unsigned v = (tid + off < 1024) ? acc[tid + off] : 0u;
    __syncthreads();
    acc[tid] += v;
    __syncthreads();
  }
  const unsigned above = acc[tid] - mysum;  // strictly-higher threads' total
  if (above < k && acc[tid] >= k) {
    unsigned cum = above;
    int binf = tid * 64;
    for (int j = 63; j >= 0; --j) {
      unsigned c = hb[tid * 64 + j];
      if (cum + c >= k) { binf = tid * 64 + j; break; }
      cum += c;
    }
    pivotf[b] = key2f(((unsigned)binf) << 16);
  }
}

// ---------------- band collect (approx scores near pivot) ----------------
__global__ void band_kernel(const float* __restrict__ scores, const float* __restrict__ pivotf,
                            int* __restrict__ bandcount, int* __restrict__ bandlist, int S) {
  int idx = blockIdx.x * 256 + threadIdx.x;
  if (idx >= NB * S) return;
  int b = idx / S, i = idx - b * S;
  if (fabsf(scores[idx] - pivotf[b]) <= BAND_TAU) {
    int slot = atomicAdd(&bandcount[b], 1);
    if (slot < BANDCAP) bandlist[b * BANDCAP + slot] = i;
  }
}

// ---------------- exact fp32 rescore of band spans ----------------
__global__ __launch_bounds__(256) void rescore_kernel(
    const float* __restrict__ emb, const int* __restrict__ spans,
    const float* __restrict__ W1, const float* __restrict__ w_s,
    const float* __restrict__ b_s, const int* __restrict__ lengths,
    const float* __restrict__ P, const float* __restrict__ Q, const float* __restrict__ R,
    const int* __restrict__ bandcount, const int* __restrict__ bandlist,
    float* __restrict__ scores, int S) {
  const int b = blockIdx.y;
  int cnt = bandcount[b];
  if (cnt > BANDCAP) cnt = BANDCAP;
  if ((int)blockIdx.x >= cnt) return;
  const int i = bandlist[b * BANDCAP + blockIdx.x];
  const int s = spans[2 * i], e = spans[2 * i + 1], wd = e - s;
  const int tid = threadIdx.x;
  __shared__ float prod[HH];
  __shared__ float red[256];
  for (int c = tid; c < HH; c += 256)
    prod[c] = emb[((size_t)b * NN + s) * HH + c] * emb[((size_t)b * NN + e) * HH + c];
  __syncthreads();
  const float* W1c = W1 + (size_t)(2 * HH) * HH;
  float psum = 0.f;
  for (int c0 = 0; c0 < HH; c0 += 256) {
    const int c = c0 + tid;
    float a = P[((size_t)b * NN + s) * HH + c] + Q[((size_t)b * NN + e) * HH + c] + R[(size_t)wd * HH + c];
    for (int k = 0; k < HH; ++k) a = fmaf(prod[k], W1c[(size_t)k * HH + c], a);
    psum = fmaf(gelu_f(a), w_s[c], psum);
  }
  red[tid] = psum;
  __syncthreads();
  for (int off = 128; off > 0; off >>= 1) {
    if (tid < off) red[tid] += red[tid + off];
    __syncthreads();
  }
  if (tid == 0) {
    float v = red[0] + b_s[0];
    if (e >= lengths[b]) v += -1000000.0f;
    scores[(size_t)b * S + i] = v;
  }
}

// ---------------- parallel candidate filter (final scores) ----------------
__global__ void filt_kernel(const float* __restrict__ scores, const float* __restrict__ pivotf,
                            int* __restrict__ filtcount, int* __restrict__ filtlist, int S) {
  int idx = blockIdx.x * 256 + threadIdx.x;
  if (idx >= NB * S) return;
  int b = idx / S, i = idx - b * S;
  if (scores[idx] > pivotf[b] - 0.01f) {
    int slot = atomicAdd(&filtcount[b], 1);
    if (slot < FILTCAP) filtlist[b * FILTCAP + slot] = i;
  }
}

// ---------------- exact top-k on candidate set (radix + rank-order) ----------------
__global__ __launch_bounds__(1024) void sel_kernel(
    const float* __restrict__ scores, const int* __restrict__ spans,
    const int* __restrict__ kptr, const int* __restrict__ filtcount,
    const int* __restrict__ filtlist,
    float* __restrict__ out_spans, int* __restrict__ sel, int S) {
  const int b = blockIdx.x;
  const int tid = threadIdx.x;
  const int k = kptr[0];
  __shared__ unsigned keys[FILTCAP];  // 24 KB
  __shared__ int idxs[FILTCAP];       // 24 KB
  __shared__ unsigned hist[256];
  __shared__ unsigned sh_prefix;
  __shared__ int sh_remaining;
  __shared__ int selcnt;
  __shared__ int slist[512];

  int M = filtcount[b];
  if (M > FILTCAP) M = FILTCAP;
  for (int i = tid; i < M; i += 1024) {
    int gi = filtlist[b * FILTCAP + i];
    idxs[i] = gi;
    keys[i] = f2key(scores[(size_t)b * S + gi]);
  }
  if (tid == 0) selcnt = 0;
  __syncthreads();

  unsigned prefix = 0;
  int remaining = k;
  for (int round = 0; round < 4; ++round) {
    const int shift = 24 - 8 * round;
    if (tid < 256) hist[tid] = 0;
    __syncthreads();
    for (int i = tid; i < M; i += 1024) {
      unsigned key = keys[i];
      if (round == 0 || (key >> (shift + 8)) == prefix)
        atomicAdd(&hist[(key >> shift) & 255u], 1u);
    }
    __syncthreads();
    if (tid == 0) {
      int cum = 0;
      for (int bin = 255; bin >= 0; --bin) {
        int c = (int)hist[bin];
        if (cum + c >= remaining) {
          sh_prefix = (prefix << 8) | (unsigned)bin;
          sh_remaining = remaining - cum;
          break;
        }
        cum += c;
      }
    }
    __syncthreads();
    prefix = sh_prefix;
    remaining = sh_remaining;
    __syncthreads();
  }
  const unsigned pk = prefix;
  const int m_eq = remaining;

  for (int i = tid; i < M; i += 1024) {
    unsigned key = keys[i];
    bool pick = false;
    if (key > pk) {
      pick = true;
    } else if (key == pk) {
      int r = 0;
      const int myidx = idxs[i];
      for (int j = 0; j < M; ++j)
        if (keys[j] == pk && idxs[j] < myidx) ++r;
      pick = (r < m_eq);  // jax tie-break: lowest index first
    }
    if (pick) {
      int p = atomicAdd(&selcnt, 1);
      if (p < 512) slist[p] = idxs[i];
    }
  }
  __syncthreads();

  // rank-order selected indices ascending; write outputs
  for (int i = tid; i < k; i += 1024) {
    const int my = slist[i];
    int r = 0;
    for (int j = 0; j < k; ++j) r += (slist[j] < my);
    sel[b * KTOP + r] = my;
    out_spans[(b * KTOP + r) * 2 + 0] = (float)spans[2 * my];
    out_spans[(b * KTOP + r) * 2 + 1] = (float)spans[2 * my + 1];
  }
}

// ---------------- gather part: fp32 (x*y)@W1c partial over K-chunk of 128 ----------------
__global__ __launch_bounds__(256) void gather_part_kernel(
    const float* __restrict__ emb, const int* __restrict__ spans,
    const float* __restrict__ W1, const int* __restrict__ sel,
    float* __restrict__ Gpart) {
  __shared__ float As[KT][ASTR];
  __shared__ float Bs[KT][BSTR];
  __shared__ int ssm[MT], eem[MT];
  const int tile = blockIdx.x;
  const int hby6 = blockIdx.y;
  const int hb = (hby6 / 6) * NT;
  const int ks = hby6 % 6;
  const int b = blockIdx.z;
  const int tid = threadIdx.x;
  const int th = tid & 31, tw = tid >> 5;
  if (tid < MT) {
    int j = tile * MT + tid;
    if (j >= KTOP) j = KTOP - 1;
    int i = sel[b * KTOP + j];
    ssm[tid] = spans[2 * i];
    eem[tid] = spans[2 * i + 1];
  }
  __syncthreads();
  const int m0 = tid >> 3, m1 = m0 + 32;
  const int d0 = (tid & 7) << 2;
  const size_t ebase = (size_t)b * NN * HH;
  const size_t rx0 = ebase + (size_t)ssm[m0] * HH;
  const size_t ry0 = ebase + (size_t)eem[m0] * HH;
  const size_t rx1 = ebase + (size_t)ssm[m1] * HH;
  const size_t ry1 = ebase + (size_t)eem[m1] * HH;
  const float* W1c = W1 + (size_t)(2 * HH) * HH;
  const int bc = (tid & 63) << 2;
  const int br = tid >> 6;
  float acc[8][8];
#pragma unroll
  for (int i = 0; i < 8; ++i)
#pragma unroll
    for (int j = 0; j < 8; ++j) acc[i][j] = 0.f;
  const int k0 = ks * 128;
  for (int it = 0; it < 4; ++it) {
    const int kt = k0 + it * KT;
    float4 x0 = *reinterpret_cast<const float4*>(emb + rx0 + kt + d0);
    float4 y0 = *reinterpret_cast<const float4*>(emb + ry0 + kt + d0);
    float4 x1 = *reinterpret_cast<const float4*>(emb + rx1 + kt + d0);
    float4 y1 = *reinterpret_cast<const float4*>(emb + ry1 + kt + d0);
    float4 bw[8];
#pragma unroll
    for (int r = 0; r < 8; ++r)
      bw[r] = *reinterpret_cast<const float4*>(W1c + (size_t)(kt + br + 4 * r) * HH + hb + bc);
    __syncthreads();
    As[d0 + 0][m0] = x0.x * y0.x; As[d0 + 1][m0] = x0.y * y0.y;
    As[d0 + 2][m0] = x0.z * y0.z; As[d0 + 3][m0] = x0.w * y0.w;
    As[d0 + 0][m1] = x1.x * y1.x; As[d0 + 1][m1] = x1.y * y1.y;
    As[d0 + 2][m1] = x1.z * y1.z; As[d0 + 3][m1] = x1.w * y1.w;
#pragma unroll
    for (int r = 0; r < 8; ++r)
      *reinterpret_cast<float4*>(&Bs[br + 4 * r][bc]) = bw[r];
    __syncthreads();
#pragma unroll
    for (int d = 0; d < KT; ++d) {
      const float4 a0 = *reinterpret_cast<const float4*>(&As[d][tw * 4]);
      const float4 a1 = *reinterpret_cast<const float4*>(&As[d][tw * 4 + 32]);
      const float4 b0 = *reinterpret_cast<const float4*>(&Bs[d][th * 4]);
      const float4 b1v = *reinterpret_cast<const float4*>(&Bs[d][th * 4 + 128]);
      const float av[8] = {a0.x, a0.y, a0.z, a0.w, a1.x, a1.y, a1.z, a1.w};
      const float bv[8] = {b0.x, b0.y, b0.z, b0.w, b1v.x, b1v.y, b1v.z, b1v.w};
#pragma unroll
      for (int mi = 0; mi < 8; ++mi)
#pragma unroll
        for (int ni = 0; ni < 8; ++ni)
          acc[mi][ni] = fmaf(av[mi], bv[ni], acc[mi][ni]);
    }
  }
#pragma unroll
  for (int mi = 0; mi < 8; ++mi) {
    const int m = tw * 4 + (mi & 3) + ((mi >> 2) << 5);
    float* op = Gpart + (((size_t)ks * NB + b) * GPAD + tile * MT + m) * HH + hb;
    *reinterpret_cast<float4*>(op + th * 4) = make_float4(acc[mi][0], acc[mi][1], acc[mi][2], acc[mi][3]);
    *reinterpret_cast<float4*>(op + th * 4 + 128) = make_float4(acc[mi][4], acc[mi][5], acc[mi][6], acc[mi][7]);
  }
}

// ---------------- gather fin: sum partials + PQR -> gelu -> h + score partials ----------------
__global__ __launch_bounds__(256) void gather_fin_kernel(
    const float* __restrict__ Gpart, const int* __restrict__ spans,
    const int* __restrict__ sel,
    const float* __restrict__ P, const float* __restrict__ Q, const float* __restrict__ R,
    const float* __restrict__ w_s, float* __restrict__ outh, float* __restrict__ spartg) {
  __shared__ int ssm[16], eem[16], wwm[16], vvm[16];
  __shared__ float sred[16];
  const int t16 = blockIdx.x;
  const int hby = blockIdx.y;
  const int b = blockIdx.z;
  const int tid = threadIdx.x;
  if (tid < 16) {
    int j = t16 * 16 + tid;
    int valid = (j < KTOP) ? 1 : 0;
    int jj = valid ? j : KTOP - 1;
    int i = sel[b * KTOP + jj];
    ssm[tid] = spans[2 * i];
    eem[tid] = spans[2 * i + 1];
    wwm[tid] = eem[tid] - ssm[tid];
    vvm[tid] = valid;
  }
  __syncthreads();
  const int row = tid >> 4;
  const int cc = tid & 15;
  const int g448 = t16 * 16 + row;
  const int co = hby * 128 + cc * 8;
  float v[8];
#pragma unroll
  for (int i = 0; i < 8; ++i) v[i] = 0.f;
#pragma unroll
  for (int ks = 0; ks < 6; ++ks) {
    const float* gp = Gpart + (((size_t)ks * NB + b) * GPAD + g448) * HH + co;
    float4 a = *(const float4*)gp;
    float4 c = *(const float4*)(gp + 4);
    v[0] += a.x; v[1] += a.y; v[2] += a.z; v[3] += a.w;
    v[4] += c.x; v[5] += c.y; v[6] += c.z; v[7] += c.w;
  }
  const int s = ssm[row], e = eem[row], wd = wwm[row];
  const float* Pp = P + ((size_t)b * NN + s) * HH + co;
  const float* Qp = Q + ((size_t)b * NN + e) * HH + co;
  const float* Rp = R + (size_t)wd * HH + co;
  float4 p0 = *(const float4*)Pp, p1 = *(const float4*)(Pp + 4);
  float4 q0 = *(const float4*)Qp, q1 = *(const float4*)(Qp + 4);
  float4 r0 = *(const float4*)Rp, r1 = *(const float4*)(Rp + 4);
  v[0] += p0.x + q0.x + r0.x; v[1] += p0.y + q0.y + r0.y;
  v[2] += p0.z + q0.z + r0.z; v[3] += p0.w + q0.w + r0.w;
  v[4] += p1.x + q1.x + r1.x; v[5] += p1.y + q1.y + r1.y;
  v[6] += p1.z + q1.z + r1.z; v[7] += p1.w + q1.w + r1.w;
  float gl[8];
#pragma unroll
  for (int i = 0; i < 8; ++i) gl[i] = gelu_f(v[i]);
  float psum = 0.f;
  if (vvm[row]) {
    const int j = t16 * 16 + row;
    float* op = outh + (size_t)(b * KTOP + j) * HH + co;
    *(float4*)op = make_float4(gl[0], gl[1], gl[2], gl[3]);
    *(float4*)(op + 4) = make_float4(gl[4], gl[5], gl[6], gl[7]);
    const float4 w0 = *(const float4*)(w_s + co);
    const float4 w1 = *(const float4*)(w_s + co + 4);
    psum = gl[0] * w0.x + gl[1] * w0.y + gl[2] * w0.z + gl[3] * w0.w +
           gl[4] * w1.x + gl[5] * w1.y + gl[6] * w1.z + gl[7] * w1.w;
  }
  psum += __shfl_xor(psum, 1);
  psum += __shfl_xor(psum, 2);
  psum += __shfl_xor(psum, 4);
  psum += __shfl_xor(psum, 8);
  const int lane = tid & 63, wv = tid >> 6;
  if ((lane & 15) == 0) sred[wv * 4 + (lane >> 4)] = psum;
  __syncthreads();
  if (tid < 16)
    spartg[(size_t)hby * (NB * SP416) + b * SP416 + t16 * 16 + tid] = sred[tid];
}

// ---------------- final scores for selected spans ----------------
__global__ void score_fin_kernel(const float* __restrict__ spartg, const int* __restrict__ sel,
                                 const int* __restrict__ spans, const float* __restrict__ b_s,
                                 const int* __restrict__ lengths, float* __restrict__ out_scores) {
  int idx = blockIdx.x * 256 + threadIdx.x;
  if (idx >= NB * KTOP) return;
  int b = idx / KTOP, j = idx - b * KTOP;
  float v = b_s[0];
#pragma unroll
  for (int hby = 0; hby < 6; ++hby)
    v += spartg[(size_t)hby * (NB * SP416) + b * SP416 + j];
  int i = sel[idx];
  if (spans[2 * i + 1] >= lengths[b]) v += -1000000.0f;
  out_scores[idx] = v;
}

extern "C" void kernel_launch(void* const* d_in, const int* in_sizes, int n_in,
                              void* d_out, int out_size, void* d_ws, size_t ws_size,
                              hipStream_t stream) {
  const float* emb = (const float*)d_in[0];
  const int* mask = (const int*)d_in[1];
  const int* spans = (const int*)d_in[2];
  const float* wemb = (const float*)d_in[3];
  const float* W1 = (const float*)d_in[4];
  const float* b1 = (const float*)d_in[5];
  const float* w_s = (const float*)d_in[6];
  const float* b_s = (const float*)d_in[7];
  const int* kptr = (const int*)d_in[8];
  const int S = in_sizes[2] / 2;  // 30285
  float* out = (float*)d_out;

  char* wp = (char*)d_ws;
  auto take = [&](size_t bytes) {
    char* p = wp;
    wp += (bytes + 63) & ~(size_t)63;
    return p;
  };
  float* Pb = (float*)take((size_t)NB * NN * HH * 4);
  float* Qb = (float*)take((size_t)NB * NN * HH * 4);
  float* Rb = (float*)take((size_t)MAXW * HH * 4);
  float* spart = (float*)take(6 * (size_t)NB * S * 4);
  float* scoresb = (float*)take((size_t)NB * S * 4);
  float* spartg = (float*)take(6 * (size_t)NB * SP416 * 4);
  float* Gpart = (float*)take(6 * (size_t)NB * GPAD * HH * 4);  // 16.5 MB
  float* pivotf = (float*)take(NB * 4);
  unsigned short* At = (unsigned short*)take((size_t)NB * CHT * 24 * 4096 * 2);  // 47 MB
  unsigned short* Bt = (unsigned short*)take((size_t)6 * 24 * 4096 * 2);
  unsigned* hist16b = (unsigned*)take((size_t)NB * 65536 * 4);  // 512 KB
  int* selb = (int*)take(NB * KTOP * 4);
  int* lengthsb = (int*)take(NB * 4);
  int* bandcount = (int*)take(NB * 4);
  int* bandlist = (int*)take((size_t)NB * BANDCAP * 4);
  int* filtcount = (int*)take(NB * 4);
  int* filtlist = (int*)take((size_t)NB * FILTCAP * 4);

  // pq_mfma hi/lo images alias the At buffer (pq phase completes before prep_a
  // first writes At — stream-ordered).
  unsigned short* AimgHi = At;
  unsigned short* AimgLo = AimgHi + (size_t)16 * 24 * 4096;
  unsigned short* BimgHi = AimgLo + (size_t)16 * 24 * 4096;
  unsigned short* BimgLo = BimgHi + (size_t)12 * 24 * 4096;

  const size_t OFF1 = (size_t)NB * KTOP * HH;    // embs
  const size_t OFF2 = OFF1 + (size_t)NB * KTOP;  // scores | spans

  const int tiles = (S + 127) / 128;  // 237

  len_kernel<<<dim3(1), dim3(256), 0, stream>>>(mask, lengthsb);
  r_kernel<<<dim3(MAXW), dim3(256), 0, stream>>>(wemb, W1, b1, Rb);
  prep_bt_kernel<<<dim3(24, 6), dim3(256), 0, stream>>>(W1, Bt);
  prep_emb_hl_kernel<<<dim3(16, 24), dim3(256), 0, stream>>>(emb, AimgHi, AimgLo);
  prep_w1ab_kernel<<<dim3(24, 12), dim3(256), 0, stream>>>(W1, BimgHi, BimgLo);
  pq_mfma_kernel<<<dim3(16, 12), dim3(256), 0, stream>>>(AimgHi, AimgLo, BimgHi, BimgLo, Pb, Qb);
  zero_kernel<<<dim3(512), dim3(256), 0, stream>>>(hist16b, bandcount, filtcount);

  for (int pass = 0; pass < 2; ++pass) {
    const int ofs = pass * CHT;
    const int nt = (pass == 0) ? CHT : (tiles - CHT);
    prep_a_kernel<<<dim3(nt, NB), dim3(256), 0, stream>>>(emb, spans, At, S, ofs);
    score_mfma3_kernel<<<dim3(nt, 6, NB), dim3(256), 0, stream>>>(
        spans, At, Bt, w_s, Pb, Qb, Rb, spart, S, ofs);
  }

  combine_kernel<<<dim3((NB * S + 255) / 256), dim3(256), 0, stream>>>(
      spart, spans, b_s, lengthsb, scoresb, S);
  hist16_kernel<<<dim3((NB * S + 255) / 256), dim3(256), 0, stream>>>(scoresb, hist16b, S);
  scan16_kernel<<<dim3(NB), dim3(1024), 0, stream>>>(hist16b, kptr, pivotf);
  band_kernel<<<dim3((NB * S + 255) / 256), dim3(256), 0, stream>>>(
      scoresb, pivotf, bandcount, bandlist, S);
  rescore_kernel<<<dim3(BANDCAP, NB), dim3(256), 0, stream>>>(
      emb, spans, W1, w_s, b_s, lengthsb, Pb, Qb, Rb, bandcount, bandlist, scoresb, S);
  filt_kernel<<<dim3((NB * S + 255) / 256), dim3(256), 0, stream>>>(
      scoresb, pivotf, filtcount, filtlist, S);
  sel_kernel<<<dim3(NB), dim3(1024), 0, stream>>>(
      scoresb, spans, kptr, filtcount, filtlist, out + OFF2, selb, S);
  gather_part_kernel<<<dim3(7, 18, NB), dim3(256), 0, stream>>>(emb, spans, W1, selb, Gpart);
  gather_fin_kernel<<<dim3(26, 6, NB), dim3(256), 0, stream>>>(
      Gpart, spans, selb, Pb, Qb, Rb, w_s, out, spartg);
  score_fin_kernel<<<dim3((NB * KTOP + 255) / 256), dim3(256), 0, stream>>>(
      spartg, selb, spans, b_s, lengthsb, out + OFF1);
}